// Round 1
// baseline (6148.849 us; speedup 1.0000x reference)
//
#include <hip/hip_runtime.h>
#include <hip/hip_bf16.h>

// ---------------- problem constants ----------------
#define B_    8
#define S_    512
#define H_    1024
#define E_    8
#define KSEL  2
#define NH    8
#define HD    64
#define HSUB  512
#define INTER 1536
#define NJOBS 16
#define EPS   1e-5f

// ---------------- ws layout (in floats) ----------------
#define H_OFF      0LL            // h = hidden+injection  (B*S*H = 4194304)
#define AUX_OFF    4194304LL      // aux loss scalar
#define RT_OFF     4194320LL      // Job table, 16 entries * 4 floats
#define PERJOB_OFF 4194432LL
#define JS         2359296LL      // per-job float stride (9 MB)
#define HS_OFF     0LL            // hs  (512*512)
#define HS2_OFF    262144LL       // hs2 (512*512)
#define CTX_OFF    524288LL       // attn ctx / mlp out (512*512)
#define BUF3_OFF   786432LL       // qkv(512*1536) / gate_up(512*3072) / out_e(512*1024)

struct Job { int b; int e; float w; float pad; };

// ---------------- reductions ----------------
static __device__ __forceinline__ float waveRedSum(float v) {
#pragma unroll
  for (int off = 32; off > 0; off >>= 1) v += __shfl_down(v, off, 64);
  return v;
}
static __device__ __forceinline__ float waveRedMax(float v) {
#pragma unroll
  for (int off = 32; off > 0; off >>= 1) v = fmaxf(v, __shfl_down(v, off, 64));
  return v;
}
// 256-thread block reductions; buf is __shared__ float[4]
static __device__ __forceinline__ float blockRedSum256(float v, float* buf) {
  v = waveRedSum(v);
  int wv = threadIdx.x >> 6;
  if ((threadIdx.x & 63) == 0) buf[wv] = v;
  __syncthreads();
  float r = buf[0] + buf[1] + buf[2] + buf[3];
  __syncthreads();
  return r;
}
static __device__ __forceinline__ float blockRedMax256(float v, float* buf) {
  v = waveRedMax(v);
  int wv = threadIdx.x >> 6;
  if ((threadIdx.x & 63) == 0) buf[wv] = v;
  __syncthreads();
  float r = fmaxf(fmaxf(buf[0], buf[1]), fmaxf(buf[2], buf[3]));
  __syncthreads();
  return r;
}

// ---------------- h = hidden + injection ----------------
__global__ __launch_bounds__(256) void k_add(const float* __restrict__ a,
                                             const float* __restrict__ b,
                                             float* __restrict__ h) {
  long long i = (long long)blockIdx.x * 1024 + (long long)threadIdx.x * 4;
  float4 x = *(const float4*)(a + i);
  float4 y = *(const float4*)(b + i);
  x.x += y.x; x.y += y.y; x.z += y.z; x.w += y.w;
  *(float4*)(h + i) = x;
}

// ---------------- routing: logits, softmax, top-2, aux loss ----------------
__global__ void k_routing(const float* __restrict__ h, const float* __restrict__ gate_w,
                          float* __restrict__ ws) {
  __shared__ float lg[64];
  int t = threadIdx.x;
  {
    int b = t >> 3, e = t & 7;
    const float* hr = h + (long long)b * (S_ * H_);   // row s=0
    const float* g = gate_w + (long long)e * H_;
    float s = 0.f;
    for (int k = 0; k < H_; k++) s += hr[k] * g[k];
    lg[t] = s;
  }
  __syncthreads();
  if (t == 0) {
    Job* rt = (Job*)(ws + RT_OFF);
    float importance[E_] = {0};
    float load[E_] = {0};
    for (int b = 0; b < B_; b++) {
      float mx = lg[b * 8];
      for (int e = 1; e < E_; e++) mx = fmaxf(mx, lg[b * 8 + e]);
      float pr[E_]; float sum = 0.f;
      for (int e = 0; e < E_; e++) { pr[e] = expf(lg[b * 8 + e] - mx); sum += pr[e]; }
      for (int e = 0; e < E_; e++) { pr[e] /= sum; importance[e] += pr[e] * (1.0f / B_); }
      int i1 = 0;
      for (int e = 1; e < E_; e++) if (pr[e] > pr[i1]) i1 = e;
      int i2 = -1;
      for (int e = 0; e < E_; e++) if (e != i1 && (i2 < 0 || pr[e] > pr[i2])) i2 = e;
      float denom = pr[i1] + pr[i2];
      if (denom < 1e-8f) denom = 1e-8f;
      Job j1; j1.b = b; j1.e = i1; j1.w = pr[i1] / denom; j1.pad = 0.f;
      Job j2; j2.b = b; j2.e = i2; j2.w = pr[i2] / denom; j2.pad = 0.f;
      rt[2 * b + 0] = j1;
      rt[2 * b + 1] = j2;
      load[i1] += 1.0f / (B_ * KSEL);
      load[i2] += 1.0f / (B_ * KSEL);
    }
    float aux = 0.f;
    for (int e = 0; e < E_; e++) aux += (float)E_ * importance[e] * load[e];
    ws[AUX_OFF] = aux;
  }
}

// ---------------- generic NT GEMM: C[m,n] = sum_k A[m,k]*W[n,k] (+epilogue) ----------------
// EPI: 0 = store, 1 = store(v + Add[m,n]), 2 = store(v * job.w)
template <int EPI>
__global__ __launch_bounds__(256) void k_gemm(
    const float* __restrict__ Abase, long long aStride, int aByB, int lda,
    const float* __restrict__ Wbase, long long wStride, int ldb,
    float* __restrict__ Cbase, long long cStride, int ldc,
    const float* __restrict__ AddBase, long long addStride, int ldadd,
    const Job* __restrict__ rt, int Kd) {
  int job = blockIdx.z;
  Job jb = rt[job];
  const float* A = Abase + (aByB ? (long long)jb.b : (long long)job) * aStride;
  const float* W = Wbase + (long long)jb.e * wStride;
  float* C = Cbase + (long long)job * cStride;
  const float* Add = (EPI == 1) ? (AddBase + (long long)job * addStride) : nullptr;

  int m0 = blockIdx.y * 64, n0 = blockIdx.x * 64;
  __shared__ float As[16][64];
  __shared__ float Bs[16][64];
  float acc[4][4] = {};
  int t = threadIdx.y * 16 + threadIdx.x;

  for (int k0 = 0; k0 < Kd; k0 += 16) {
#pragma unroll
    for (int c = 0; c < 4; c++) {
      int idx = t + c * 256;
      int m = idx >> 4, kk = idx & 15;
      As[kk][m] = A[(long long)(m0 + m) * lda + k0 + kk];
      Bs[kk][m] = W[(long long)(n0 + m) * ldb + k0 + kk];
    }
    __syncthreads();
#pragma unroll
    for (int kk = 0; kk < 16; kk++) {
      float a[4], b[4];
#pragma unroll
      for (int c = 0; c < 4; c++) a[c] = As[kk][threadIdx.y * 4 + c];
#pragma unroll
      for (int c = 0; c < 4; c++) b[c] = Bs[kk][threadIdx.x * 4 + c];
#pragma unroll
      for (int ci = 0; ci < 4; ci++)
#pragma unroll
        for (int cj = 0; cj < 4; cj++)
          acc[ci][cj] = fmaf(a[ci], b[cj], acc[ci][cj]);
    }
    __syncthreads();
  }

#pragma unroll
  for (int ci = 0; ci < 4; ci++) {
    int m = m0 + threadIdx.y * 4 + ci;
#pragma unroll
    for (int cj = 0; cj < 4; cj++) {
      int n = n0 + threadIdx.x * 4 + cj;
      float v = acc[ci][cj];
      if (EPI == 1) v += Add[(long long)m * ldadd + n];
      if (EPI == 2) v *= jb.w;
      C[(long long)m * ldc + n] = v;
    }
  }
}

// ---------------- RoPE in-place on q,k of qkv buffer ----------------
__global__ __launch_bounds__(256) void k_rope(float* __restrict__ ws,
                                              const float* __restrict__ cosT,
                                              const float* __restrict__ sinT) {
  int i = blockIdx.x;     // seq row
  int job = blockIdx.y;
  float* qkv = ws + PERJOB_OFF + (long long)job * JS + BUF3_OFF;
  int t = threadIdx.x;    // 256 = 8 heads * 32 pairs
  int head = t >> 5, d = t & 31;
  int col = head * 64 + d;
  float c1 = cosT[i * 64 + d], c2 = cosT[i * 64 + d + 32];
  float s1 = sinT[i * 64 + d], s2 = sinT[i * 64 + d + 32];
  float* row = qkv + (long long)i * 1536;
  // q
  float x1 = row[col], x2 = row[col + 32];
  row[col] = x1 * c1 - x2 * s1;
  row[col + 32] = x2 * c2 + x1 * s2;
  // k
  float y1 = row[512 + col], y2 = row[512 + col + 32];
  row[512 + col] = y1 * c1 - y2 * s1;
  row[512 + col + 32] = y2 * c2 + y1 * s2;
}

// ---------------- attention: one block per (query row, head, job) ----------------
__global__ __launch_bounds__(256) void k_attn(float* __restrict__ ws) {
  const int i = blockIdx.x;     // query row
  const int head = blockIdx.y;
  const int job = blockIdx.z;
  float* base = ws + PERJOB_OFF + (long long)job * JS;
  const float* qkv = base + BUF3_OFF;
  float* ctx = base + CTX_OFF;
  const int t = threadIdx.x;

  __shared__ float q[64];
  __shared__ float Ks[128][65];
  __shared__ float p[512];
  __shared__ float red[256];
  __shared__ float sbuf[4];

  if (t < 64) q[t] = qkv[(long long)i * 1536 + head * 64 + t];
  __syncthreads();

  // scores, K-tile staged in LDS
  for (int tile = 0; tile < 4; tile++) {
#pragma unroll
    for (int c = 0; c < 32; c++) {
      int idx = t + c * 256;
      int r = idx >> 6, d = idx & 63;
      Ks[r][d] = qkv[(long long)(tile * 128 + r) * 1536 + 512 + head * 64 + d];
    }
    __syncthreads();
    if (t < 128) {
      float s = 0.f;
#pragma unroll
      for (int d = 0; d < 64; d++) s += q[d] * Ks[t][d];
      p[tile * 128 + t] = s * 0.125f;
    }
    __syncthreads();
  }

  // softmax over 512
  float s0 = p[t], s1 = p[t + 256];
  float m = blockRedMax256(fmaxf(s0, s1), sbuf);
  float e0 = expf(s0 - m), e1 = expf(s1 - m);
  float l = blockRedSum256(e0 + e1, sbuf);
  p[t] = e0;
  p[t + 256] = e1;
  __syncthreads();

  // PV: 4 thread-groups over j, 64 dims
  int d = t & 63, g = t >> 6;
  float acc = 0.f;
  const float* vbase = qkv + 1024 + head * 64 + d;
  for (int jj = g * 128; jj < g * 128 + 128; jj++)
    acc += p[jj] * vbase[(long long)jj * 1536];
  red[t] = acc;
  __syncthreads();
  if (t < 64) {
    float o = (red[t] + red[t + 64] + red[t + 128] + red[t + 192]) / l;
    ctx[(long long)i * 512 + head * 64 + t] = o;
  }
}

// ---------------- in-place RMSNorm over rows of 512 ----------------
__global__ __launch_bounds__(256) void k_rms512(float* __restrict__ base, long long jobStride) {
  float* x = base + (long long)blockIdx.y * jobStride + (long long)blockIdx.x * 512;
  int t = threadIdx.x;
  __shared__ float buf[4];
  float a0 = x[t], a1 = x[t + 256];
  float ss = blockRedSum256(a0 * a0 + a1 * a1, buf);
  float r = rsqrtf(ss * (1.0f / 512.0f) + EPS);
  x[t] = a0 * r;
  x[t + 256] = a1 * r;
}

// ---------------- silu(gate)*up in-place in buf3 ----------------
__global__ __launch_bounds__(256) void k_silu(float* __restrict__ ws) {
  int job = blockIdx.y;
  float* buf3 = ws + PERJOB_OFF + (long long)job * JS + BUF3_OFF;
  int idx = blockIdx.x * 256 + threadIdx.x;   // 0 .. 512*1536-1
  int s = idx / 1536, c = idx - s * 1536;
  float g = buf3[(long long)s * 3072 + c];
  float u = buf3[(long long)s * 3072 + 1536 + c];
  float sig = 1.0f / (1.0f + expf(-g));
  buf3[(long long)s * 3072 + c] = g * sig * u;
}

// ---------------- final: out = rms_norm(h + w1*out_e1 + w2*out_e2), plus aux ----------------
__global__ __launch_bounds__(256) void k_final(const float* __restrict__ ws,
                                               float* __restrict__ out, int auxIdx) {
  int row = blockIdx.x;              // 0 .. B*S-1
  int b = row >> 9;
  int s = row & 511;
  const float* hr = ws + H_OFF + (long long)row * H_;
  const float* o1 = ws + PERJOB_OFF + (long long)(2 * b) * JS + BUF3_OFF + (long long)s * H_;
  const float* o2 = ws + PERJOB_OFF + (long long)(2 * b + 1) * JS + BUF3_OFF + (long long)s * H_;
  int t = threadIdx.x;
  __shared__ float buf[4];
  float v[4];
  float ss = 0.f;
#pragma unroll
  for (int c = 0; c < 4; c++) {
    int d = t + c * 256;
    v[c] = hr[d] + o1[d] + o2[d];
    ss += v[c] * v[c];
  }
  ss = blockRedSum256(ss, buf);
  float r = rsqrtf(ss * (1.0f / (float)H_) + EPS);
#pragma unroll
  for (int c = 0; c < 4; c++)
    out[(long long)row * H_ + t + c * 256] = v[c] * r;
  if (row == 0 && t == 0) out[auxIdx] = ws[AUX_OFF];
}

// ---------------- launch ----------------
extern "C" void kernel_launch(void* const* d_in, const int* in_sizes, int n_in,
                              void* d_out, int out_size, void* d_ws, size_t ws_size,
                              hipStream_t stream) {
  const float* hidden = (const float*)d_in[0];
  const float* inj    = (const float*)d_in[1];
  const float* cosT   = (const float*)d_in[2];
  const float* sinT   = (const float*)d_in[3];
  const float* gate_w = (const float*)d_in[4];
  const float* down_w = (const float*)d_in[5];
  const float* up_w   = (const float*)d_in[6];
  const float* qkv_w  = (const float*)d_in[7];
  const float* o_w    = (const float*)d_in[8];
  const float* gup_w  = (const float*)d_in[9];
  const float* mdw    = (const float*)d_in[10];
  float* out = (float*)d_out;
  float* ws  = (float*)d_ws;

  float* h    = ws + H_OFF;
  const Job* rt = (const Job*)(ws + RT_OFF);
  float* hsB  = ws + PERJOB_OFF + HS_OFF;
  float* hs2B = ws + PERJOB_OFF + HS2_OFF;
  float* ctxB = ws + PERJOB_OFF + CTX_OFF;
  float* b3B  = ws + PERJOB_OFF + BUF3_OFF;

  dim3 tb(16, 16);

  k_add<<<4096, 256, 0, stream>>>(hidden, inj, h);
  k_routing<<<1, 64, 0, stream>>>(h, gate_w, ws);

  // hs = h[b] @ down_w[e].T            (512x512, K=1024)
  k_gemm<0><<<dim3(8, 8, NJOBS), tb, 0, stream>>>(
      h, (long long)S_ * H_, 1, H_,
      down_w, (long long)HSUB * H_, H_,
      hsB, JS, HSUB, nullptr, 0, 0, rt, H_);

  // qkv = hs @ qkv_w[e].T              (512x1536, K=512)
  k_gemm<0><<<dim3(24, 8, NJOBS), tb, 0, stream>>>(
      hsB, JS, 0, HSUB,
      qkv_w, (long long)3 * NH * HD * HSUB, HSUB,
      b3B, JS, 1536, nullptr, 0, 0, rt, HSUB);

  k_rope<<<dim3(S_, NJOBS), 256, 0, stream>>>(ws, cosT, sinT);
  k_attn<<<dim3(S_, NH, NJOBS), 256, 0, stream>>>(ws);

  // hs2 = hs + ctx @ o_w[e].T          (512x512, K=512)
  k_gemm<1><<<dim3(8, 8, NJOBS), tb, 0, stream>>>(
      ctxB, JS, 0, HSUB,
      o_w, (long long)HSUB * HSUB, HSUB,
      hs2B, JS, HSUB, hsB, JS, HSUB, rt, HSUB);
  k_rms512<<<dim3(S_, NJOBS), 256, 0, stream>>>(hs2B, JS);

  // gate_up = hs2 @ gup_w[e].T         (512x3072, K=512)
  k_gemm<0><<<dim3(48, 8, NJOBS), tb, 0, stream>>>(
      hs2B, JS, 0, HSUB,
      gup_w, (long long)2 * INTER * HSUB, HSUB,
      b3B, JS, 3072, nullptr, 0, 0, rt, HSUB);
  k_silu<<<dim3(3072, NJOBS), 256, 0, stream>>>(ws);

  // ctx = hs2 + act @ mdw[e].T         (512x512, K=1536, act ld=3072)
  k_gemm<1><<<dim3(8, 8, NJOBS), tb, 0, stream>>>(
      b3B, JS, 0, 3072,
      mdw, (long long)HSUB * INTER, INTER,
      ctxB, JS, HSUB, hs2B, JS, HSUB, rt, INTER);
  k_rms512<<<dim3(S_, NJOBS), 256, 0, stream>>>(ctxB, JS);

  // out_e (scaled by job weight) = hs3 @ up_w[e].T   (512x1024, K=512) -> buf3
  k_gemm<2><<<dim3(16, 8, NJOBS), tb, 0, stream>>>(
      ctxB, JS, 0, HSUB,
      up_w, (long long)H_ * HSUB, HSUB,
      b3B, JS, H_, nullptr, 0, 0, rt, HSUB);

  k_final<<<B_ * S_, 256, 0, stream>>>(ws, out, out_size - 1);
}

// Round 2
// 1503.270 us; speedup vs baseline: 4.0903x; 4.0903x over previous
//
#include <hip/hip_runtime.h>
#include <hip/hip_bf16.h>

// ---------------- problem constants ----------------
#define B_    8
#define S_    512
#define H_    1024
#define E_    8
#define KSEL  2
#define NH    8
#define HD    64
#define HSUB  512
#define INTER 1536
#define NJOBS 16
#define EPS   1e-5f

// ---------------- ws layout (in floats) ----------------
#define H_OFF      0LL            // h = hidden+injection  (B*S*H = 4194304)
#define AUX_OFF    4194304LL      // aux loss scalar
#define RT_OFF     4194320LL      // Job table, 16 entries * 4 floats
#define PERJOB_OFF 4194432LL
#define JS         2359296LL      // per-job float stride (9 MB)
#define HS_OFF     0LL            // hs  (512*512)
#define HS2_OFF    262144LL       // hs2 (512*512)
#define CTX_OFF    524288LL       // attn ctx / mlp out (512*512)
#define BUF3_OFF   786432LL       // qkv(512*1536) / gate_up(512*3072) / out_e(512*1024)

struct Job { int b; int e; float w; float pad; };

// ---------------- reductions ----------------
static __device__ __forceinline__ float waveRedSum(float v) {
#pragma unroll
  for (int off = 32; off > 0; off >>= 1) v += __shfl_down(v, off, 64);
  return v;
}
static __device__ __forceinline__ float blockRedSum256(float v, float* buf) {
  v = waveRedSum(v);
  int wv = threadIdx.x >> 6;
  if ((threadIdx.x & 63) == 0) buf[wv] = v;
  __syncthreads();
  float r = buf[0] + buf[1] + buf[2] + buf[3];
  __syncthreads();
  return r;
}

// ---------------- h = hidden + injection ----------------
__global__ __launch_bounds__(256) void k_add(const float* __restrict__ a,
                                             const float* __restrict__ b,
                                             float* __restrict__ h) {
  long long i = (long long)blockIdx.x * 1024 + (long long)threadIdx.x * 4;
  float4 x = *(const float4*)(a + i);
  float4 y = *(const float4*)(b + i);
  x.x += y.x; x.y += y.y; x.z += y.z; x.w += y.w;
  *(float4*)(h + i) = x;
}

// ---------------- routing: logits, softmax, top-2, aux loss ----------------
__global__ void k_routing(const float* __restrict__ h, const float* __restrict__ gate_w,
                          float* __restrict__ ws) {
  __shared__ float lg[64];
  int t = threadIdx.x;
  {
    int b = t >> 3, e = t & 7;
    const float* hr = h + (long long)b * (S_ * H_);   // row s=0
    const float* g = gate_w + (long long)e * H_;
    float s = 0.f;
    for (int k = 0; k < H_; k++) s += hr[k] * g[k];
    lg[t] = s;
  }
  __syncthreads();
  if (t == 0) {
    Job* rt = (Job*)(ws + RT_OFF);
    float importance[E_] = {0};
    float load[E_] = {0};
    for (int b = 0; b < B_; b++) {
      float mx = lg[b * 8];
      for (int e = 1; e < E_; e++) mx = fmaxf(mx, lg[b * 8 + e]);
      float pr[E_]; float sum = 0.f;
      for (int e = 0; e < E_; e++) { pr[e] = expf(lg[b * 8 + e] - mx); sum += pr[e]; }
      for (int e = 0; e < E_; e++) { pr[e] /= sum; importance[e] += pr[e] * (1.0f / B_); }
      int i1 = 0;
      for (int e = 1; e < E_; e++) if (pr[e] > pr[i1]) i1 = e;
      int i2 = -1;
      for (int e = 0; e < E_; e++) if (e != i1 && (i2 < 0 || pr[e] > pr[i2])) i2 = e;
      float denom = pr[i1] + pr[i2];
      if (denom < 1e-8f) denom = 1e-8f;
      Job j1; j1.b = b; j1.e = i1; j1.w = pr[i1] / denom; j1.pad = 0.f;
      Job j2; j2.b = b; j2.e = i2; j2.w = pr[i2] / denom; j2.pad = 0.f;
      rt[2 * b + 0] = j1;
      rt[2 * b + 1] = j2;
      load[i1] += 1.0f / (B_ * KSEL);
      load[i2] += 1.0f / (B_ * KSEL);
    }
    float aux = 0.f;
    for (int e = 0; e < E_; e++) aux += (float)E_ * importance[e] * load[e];
    ws[AUX_OFF] = aux;
  }
}

// ---------------- generic NT GEMM: C[m,n] = sum_k A[m,k]*W[n,k] (+epilogue) ----------------
// EPI: 0 = store, 1 = store(v + Add[m,n]), 2 = store(v * job.w)
template <int EPI>
__global__ __launch_bounds__(256) void k_gemm(
    const float* __restrict__ Abase, long long aStride, int aByB, int lda,
    const float* __restrict__ Wbase, long long wStride, int ldb,
    float* __restrict__ Cbase, long long cStride, int ldc,
    const float* __restrict__ AddBase, long long addStride, int ldadd,
    const Job* __restrict__ rt, int Kd) {
  int job = blockIdx.z;
  Job jb = rt[job];
  const float* A = Abase + (aByB ? (long long)jb.b : (long long)job) * aStride;
  const float* W = Wbase + (long long)jb.e * wStride;
  float* C = Cbase + (long long)job * cStride;
  const float* Add = (EPI == 1) ? (AddBase + (long long)job * addStride) : nullptr;

  int m0 = blockIdx.y * 64, n0 = blockIdx.x * 64;
  __shared__ __align__(16) float As[16][64];
  __shared__ __align__(16) float Bs[16][64];
  float acc[4][4] = {};
  int t = threadIdx.y * 16 + threadIdx.x;
  // staging indices: each thread loads one float4 of A and one of W per k-step
  const int sm = t >> 2;            // 0..63  (row within tile)
  const int sk4 = (t & 3) << 2;     // 0,4,8,12

  for (int k0 = 0; k0 < Kd; k0 += 16) {
    {
      float4 av = *(const float4*)(A + (long long)(m0 + sm) * lda + k0 + sk4);
      float4 wv = *(const float4*)(W + (long long)(n0 + sm) * ldb + k0 + sk4);
      As[sk4 + 0][sm] = av.x; As[sk4 + 1][sm] = av.y;
      As[sk4 + 2][sm] = av.z; As[sk4 + 3][sm] = av.w;
      Bs[sk4 + 0][sm] = wv.x; Bs[sk4 + 1][sm] = wv.y;
      Bs[sk4 + 2][sm] = wv.z; Bs[sk4 + 3][sm] = wv.w;
    }
    __syncthreads();
#pragma unroll
    for (int kk = 0; kk < 16; kk++) {
      float4 a4 = *(const float4*)&As[kk][threadIdx.y * 4];
      float4 b4 = *(const float4*)&Bs[kk][threadIdx.x * 4];
      acc[0][0] = fmaf(a4.x, b4.x, acc[0][0]);
      acc[0][1] = fmaf(a4.x, b4.y, acc[0][1]);
      acc[0][2] = fmaf(a4.x, b4.z, acc[0][2]);
      acc[0][3] = fmaf(a4.x, b4.w, acc[0][3]);
      acc[1][0] = fmaf(a4.y, b4.x, acc[1][0]);
      acc[1][1] = fmaf(a4.y, b4.y, acc[1][1]);
      acc[1][2] = fmaf(a4.y, b4.z, acc[1][2]);
      acc[1][3] = fmaf(a4.y, b4.w, acc[1][3]);
      acc[2][0] = fmaf(a4.z, b4.x, acc[2][0]);
      acc[2][1] = fmaf(a4.z, b4.y, acc[2][1]);
      acc[2][2] = fmaf(a4.z, b4.z, acc[2][2]);
      acc[2][3] = fmaf(a4.z, b4.w, acc[2][3]);
      acc[3][0] = fmaf(a4.w, b4.x, acc[3][0]);
      acc[3][1] = fmaf(a4.w, b4.y, acc[3][1]);
      acc[3][2] = fmaf(a4.w, b4.z, acc[3][2]);
      acc[3][3] = fmaf(a4.w, b4.w, acc[3][3]);
    }
    __syncthreads();
  }

#pragma unroll
  for (int ci = 0; ci < 4; ci++) {
    int m = m0 + threadIdx.y * 4 + ci;
#pragma unroll
    for (int cj = 0; cj < 4; cj++) {
      int n = n0 + threadIdx.x * 4 + cj;
      float v = acc[ci][cj];
      if (EPI == 1) v += Add[(long long)m * ldadd + n];
      if (EPI == 2) v *= jb.w;
      C[(long long)m * ldc + n] = v;
    }
  }
}

// ---------------- RoPE in-place on q,k of qkv buffer ----------------
__global__ __launch_bounds__(256) void k_rope(float* __restrict__ ws,
                                              const float* __restrict__ cosT,
                                              const float* __restrict__ sinT) {
  int i = blockIdx.x;     // seq row
  int job = blockIdx.y;
  float* qkv = ws + PERJOB_OFF + (long long)job * JS + BUF3_OFF;
  int t = threadIdx.x;    // 256 = 8 heads * 32 pairs
  int head = t >> 5, d = t & 31;
  int col = head * 64 + d;
  float c1 = cosT[i * 64 + d], c2 = cosT[i * 64 + d + 32];
  float s1 = sinT[i * 64 + d], s2 = sinT[i * 64 + d + 32];
  float* row = qkv + (long long)i * 1536;
  // q
  float x1 = row[col], x2 = row[col + 32];
  row[col] = x1 * c1 - x2 * s1;
  row[col + 32] = x2 * c2 + x1 * s2;
  // k
  float y1 = row[512 + col], y2 = row[512 + col + 32];
  row[512 + col] = y1 * c1 - y2 * s1;
  row[512 + col + 32] = y2 * c2 + y1 * s2;
}

// ---------------- flash attention: one block per (64-row q-tile, head, job) ----------------
__global__ __launch_bounds__(256) void k_attn2(float* __restrict__ ws) {
  const int qt = blockIdx.x;      // 0..7 (q tile of 64 rows)
  const int head = blockIdx.y;
  const int job = blockIdx.z;
  float* base = ws + PERJOB_OFF + (long long)job * JS;
  const float* qkv = base + BUF3_OFF;
  float* ctx = base + CTX_OFF;
  const int t = threadIdx.x;
  const int tx = t & 15, ty = t >> 4;
  const int q0 = qt * 64;
  const float* hb = qkv + head * 64;

  __shared__ float Qs[64][65];   // [d][m]  (transposed)
  __shared__ float Ks[64][65];   // [d][n]  (transposed)
  __shared__ float Vs[64][65];   // [kk][d] (row-major)
  __shared__ float Ps[64][66];   // [m][kk]

  // stage Q^T (float4 global, scalar LDS writes — 2-way max with pad 65)
#pragma unroll
  for (int c = 0; c < 4; c++) {
    int qi = c * 256 + t;
    int m = qi >> 4, d4 = (qi & 15) << 2;
    float4 v = *(const float4*)(hb + (long long)(q0 + m) * 1536 + d4);
    Qs[d4 + 0][m] = v.x; Qs[d4 + 1][m] = v.y; Qs[d4 + 2][m] = v.z; Qs[d4 + 3][m] = v.w;
  }

  float acc[4][4] = {};
  float mrun[4] = {-1e30f, -1e30f, -1e30f, -1e30f};
  float lrun[4] = {0.f, 0.f, 0.f, 0.f};

  for (int kt = 0; kt < 8; kt++) {
    const int k0 = kt * 64;
#pragma unroll
    for (int c = 0; c < 4; c++) {
      int qi = c * 256 + t;
      int m = qi >> 4, d4 = (qi & 15) << 2;
      const float* rb = hb + (long long)(k0 + m) * 1536;
      float4 kv = *(const float4*)(rb + 512 + d4);
      float4 vv = *(const float4*)(rb + 1024 + d4);
      Ks[d4 + 0][m] = kv.x; Ks[d4 + 1][m] = kv.y; Ks[d4 + 2][m] = kv.z; Ks[d4 + 3][m] = kv.w;
      Vs[m][d4 + 0] = vv.x; Vs[m][d4 + 1] = vv.y; Vs[m][d4 + 2] = vv.z; Vs[m][d4 + 3] = vv.w;
    }
    __syncthreads();

    // S tile = Q K^T (4x4 per thread)
    float s[4][4] = {};
#pragma unroll 4
    for (int d = 0; d < 64; d++) {
      float a0 = Qs[d][ty * 4 + 0], a1 = Qs[d][ty * 4 + 1],
            a2 = Qs[d][ty * 4 + 2], a3 = Qs[d][ty * 4 + 3];
      float b0 = Ks[d][tx * 4 + 0], b1 = Ks[d][tx * 4 + 1],
            b2 = Ks[d][tx * 4 + 2], b3 = Ks[d][tx * 4 + 3];
      s[0][0] = fmaf(a0, b0, s[0][0]); s[0][1] = fmaf(a0, b1, s[0][1]);
      s[0][2] = fmaf(a0, b2, s[0][2]); s[0][3] = fmaf(a0, b3, s[0][3]);
      s[1][0] = fmaf(a1, b0, s[1][0]); s[1][1] = fmaf(a1, b1, s[1][1]);
      s[1][2] = fmaf(a1, b2, s[1][2]); s[1][3] = fmaf(a1, b3, s[1][3]);
      s[2][0] = fmaf(a2, b0, s[2][0]); s[2][1] = fmaf(a2, b1, s[2][1]);
      s[2][2] = fmaf(a2, b2, s[2][2]); s[2][3] = fmaf(a2, b3, s[2][3]);
      s[3][0] = fmaf(a3, b0, s[3][0]); s[3][1] = fmaf(a3, b1, s[3][1]);
      s[3][2] = fmaf(a3, b2, s[3][2]); s[3][3] = fmaf(a3, b3, s[3][3]);
    }

    // online softmax (row stats across the 16 tx lanes — contiguous within a wave)
#pragma unroll
    for (int i = 0; i < 4; i++) {
      float rm = fmaxf(fmaxf(s[i][0], s[i][1]), fmaxf(s[i][2], s[i][3])) * 0.125f;
#pragma unroll
      for (int off = 8; off > 0; off >>= 1) rm = fmaxf(rm, __shfl_xor(rm, off, 16));
      float mnew = fmaxf(mrun[i], rm);
      float sc = __expf(mrun[i] - mnew);
      float rs = 0.f;
#pragma unroll
      for (int j = 0; j < 4; j++) {
        float p = __expf(fmaf(s[i][j], 0.125f, -mnew));
        s[i][j] = p; rs += p;
      }
#pragma unroll
      for (int off = 8; off > 0; off >>= 1) rs += __shfl_xor(rs, off, 16);
      lrun[i] = lrun[i] * sc + rs;
      mrun[i] = mnew;
#pragma unroll
      for (int j = 0; j < 4; j++) acc[i][j] *= sc;
      Ps[ty * 4 + i][tx * 4 + 0] = s[i][0];
      Ps[ty * 4 + i][tx * 4 + 1] = s[i][1];
      Ps[ty * 4 + i][tx * 4 + 2] = s[i][2];
      Ps[ty * 4 + i][tx * 4 + 3] = s[i][3];
    }
    __syncthreads();

    // acc += P @ V
#pragma unroll 4
    for (int kk = 0; kk < 64; kk++) {
      float a0 = Ps[ty * 4 + 0][kk], a1 = Ps[ty * 4 + 1][kk],
            a2 = Ps[ty * 4 + 2][kk], a3 = Ps[ty * 4 + 3][kk];
      float b0 = Vs[kk][tx * 4 + 0], b1 = Vs[kk][tx * 4 + 1],
            b2 = Vs[kk][tx * 4 + 2], b3 = Vs[kk][tx * 4 + 3];
      acc[0][0] = fmaf(a0, b0, acc[0][0]); acc[0][1] = fmaf(a0, b1, acc[0][1]);
      acc[0][2] = fmaf(a0, b2, acc[0][2]); acc[0][3] = fmaf(a0, b3, acc[0][3]);
      acc[1][0] = fmaf(a1, b0, acc[1][0]); acc[1][1] = fmaf(a1, b1, acc[1][1]);
      acc[1][2] = fmaf(a1, b2, acc[1][2]); acc[1][3] = fmaf(a1, b3, acc[1][3]);
      acc[2][0] = fmaf(a2, b0, acc[2][0]); acc[2][1] = fmaf(a2, b1, acc[2][1]);
      acc[2][2] = fmaf(a2, b2, acc[2][2]); acc[2][3] = fmaf(a2, b3, acc[2][3]);
      acc[3][0] = fmaf(a3, b0, acc[3][0]); acc[3][1] = fmaf(a3, b1, acc[3][1]);
      acc[3][2] = fmaf(a3, b2, acc[3][2]); acc[3][3] = fmaf(a3, b3, acc[3][3]);
    }
    __syncthreads();
  }

#pragma unroll
  for (int i = 0; i < 4; i++) {
    float inv = 1.0f / lrun[i];
#pragma unroll
    for (int j = 0; j < 4; j++)
      ctx[(long long)(q0 + ty * 4 + i) * 512 + head * 64 + tx * 4 + j] = acc[i][j] * inv;
  }
}

// ---------------- in-place RMSNorm over rows of 512 ----------------
__global__ __launch_bounds__(256) void k_rms512(float* __restrict__ base, long long jobStride) {
  float* x = base + (long long)blockIdx.y * jobStride + (long long)blockIdx.x * 512;
  int t = threadIdx.x;
  __shared__ float buf[4];
  float a0 = x[t], a1 = x[t + 256];
  float ss = blockRedSum256(a0 * a0 + a1 * a1, buf);
  float r = rsqrtf(ss * (1.0f / 512.0f) + EPS);
  x[t] = a0 * r;
  x[t + 256] = a1 * r;
}

// ---------------- silu(gate)*up in-place in buf3 ----------------
__global__ __launch_bounds__(256) void k_silu(float* __restrict__ ws) {
  int job = blockIdx.y;
  float* buf3 = ws + PERJOB_OFF + (long long)job * JS + BUF3_OFF;
  int idx = blockIdx.x * 256 + threadIdx.x;   // 0 .. 512*1536-1
  int s = idx / 1536, c = idx - s * 1536;
  float g = buf3[(long long)s * 3072 + c];
  float u = buf3[(long long)s * 3072 + 1536 + c];
  float sig = 1.0f / (1.0f + expf(-g));
  buf3[(long long)s * 3072 + c] = g * sig * u;
}

// ---------------- final: out = rms_norm(h + w1*out_e1 + w2*out_e2), plus aux ----------------
__global__ __launch_bounds__(256) void k_final(const float* __restrict__ ws,
                                               float* __restrict__ out, int auxIdx) {
  int row = blockIdx.x;              // 0 .. B*S-1
  int b = row >> 9;
  int s = row & 511;
  const float* hr = ws + H_OFF + (long long)row * H_;
  const float* o1 = ws + PERJOB_OFF + (long long)(2 * b) * JS + BUF3_OFF + (long long)s * H_;
  const float* o2 = ws + PERJOB_OFF + (long long)(2 * b + 1) * JS + BUF3_OFF + (long long)s * H_;
  int t = threadIdx.x;
  __shared__ float buf[4];
  float v[4];
  float ss = 0.f;
#pragma unroll
  for (int c = 0; c < 4; c++) {
    int d = t + c * 256;
    v[c] = hr[d] + o1[d] + o2[d];
    ss += v[c] * v[c];
  }
  ss = blockRedSum256(ss, buf);
  float r = rsqrtf(ss * (1.0f / (float)H_) + EPS);
#pragma unroll
  for (int c = 0; c < 4; c++)
    out[(long long)row * H_ + t + c * 256] = v[c] * r;
  if (row == 0 && t == 0) out[auxIdx] = ws[AUX_OFF];
}

// ---------------- launch ----------------
extern "C" void kernel_launch(void* const* d_in, const int* in_sizes, int n_in,
                              void* d_out, int out_size, void* d_ws, size_t ws_size,
                              hipStream_t stream) {
  const float* hidden = (const float*)d_in[0];
  const float* inj    = (const float*)d_in[1];
  const float* cosT   = (const float*)d_in[2];
  const float* sinT   = (const float*)d_in[3];
  const float* gate_w = (const float*)d_in[4];
  const float* down_w = (const float*)d_in[5];
  const float* up_w   = (const float*)d_in[6];
  const float* qkv_w  = (const float*)d_in[7];
  const float* o_w    = (const float*)d_in[8];
  const float* gup_w  = (const float*)d_in[9];
  const float* mdw    = (const float*)d_in[10];
  float* out = (float*)d_out;
  float* ws  = (float*)d_ws;

  float* h    = ws + H_OFF;
  const Job* rt = (const Job*)(ws + RT_OFF);
  float* hsB  = ws + PERJOB_OFF + HS_OFF;
  float* hs2B = ws + PERJOB_OFF + HS2_OFF;
  float* ctxB = ws + PERJOB_OFF + CTX_OFF;
  float* b3B  = ws + PERJOB_OFF + BUF3_OFF;

  dim3 tb(16, 16);

  k_add<<<4096, 256, 0, stream>>>(hidden, inj, h);
  k_routing<<<1, 64, 0, stream>>>(h, gate_w, ws);

  // hs = h[b] @ down_w[e].T            (512x512, K=1024)
  k_gemm<0><<<dim3(8, 8, NJOBS), tb, 0, stream>>>(
      h, (long long)S_ * H_, 1, H_,
      down_w, (long long)HSUB * H_, H_,
      hsB, JS, HSUB, nullptr, 0, 0, rt, H_);

  // qkv = hs @ qkv_w[e].T              (512x1536, K=512)
  k_gemm<0><<<dim3(24, 8, NJOBS), tb, 0, stream>>>(
      hsB, JS, 0, HSUB,
      qkv_w, (long long)3 * NH * HD * HSUB, HSUB,
      b3B, JS, 1536, nullptr, 0, 0, rt, HSUB);

  k_rope<<<dim3(S_, NJOBS), 256, 0, stream>>>(ws, cosT, sinT);
  k_attn2<<<dim3(8, NH, NJOBS), 256, 0, stream>>>(ws);

  // hs2 = hs + ctx @ o_w[e].T          (512x512, K=512)
  k_gemm<1><<<dim3(8, 8, NJOBS), tb, 0, stream>>>(
      ctxB, JS, 0, HSUB,
      o_w, (long long)HSUB * HSUB, HSUB,
      hs2B, JS, HSUB, hsB, JS, HSUB, rt, HSUB);
  k_rms512<<<dim3(S_, NJOBS), 256, 0, stream>>>(hs2B, JS);

  // gate_up = hs2 @ gup_w[e].T         (512x3072, K=512)
  k_gemm<0><<<dim3(48, 8, NJOBS), tb, 0, stream>>>(
      hs2B, JS, 0, HSUB,
      gup_w, (long long)2 * INTER * HSUB, HSUB,
      b3B, JS, 3072, nullptr, 0, 0, rt, HSUB);
  k_silu<<<dim3(3072, NJOBS), 256, 0, stream>>>(ws);

  // ctx = hs2 + act @ mdw[e].T         (512x512, K=1536, act ld=3072)
  k_gemm<1><<<dim3(8, 8, NJOBS), tb, 0, stream>>>(
      b3B, JS, 0, 3072,
      mdw, (long long)HSUB * INTER, INTER,
      ctxB, JS, HSUB, hs2B, JS, HSUB, rt, INTER);
  k_rms512<<<dim3(S_, NJOBS), 256, 0, stream>>>(ctxB, JS);

  // out_e (scaled by job weight) = hs3 @ up_w[e].T   (512x1024, K=512) -> buf3
  k_gemm<2><<<dim3(16, 8, NJOBS), tb, 0, stream>>>(
      ctxB, JS, 0, HSUB,
      up_w, (long long)H_ * HSUB, HSUB,
      b3B, JS, H_, nullptr, 0, 0, rt, HSUB);

  k_final<<<B_ * S_, 256, 0, stream>>>(ws, out, out_size - 1);
}

// Round 8
// 625.203 us; speedup vs baseline: 9.8350x; 2.4044x over previous
//
#include <hip/hip_runtime.h>
#include <hip/hip_bf16.h>

// ---------------- problem constants ----------------
#define B_    8
#define S_    512
#define H_    1024
#define E_    8
#define NH    8
#define HD    64
#define HSUB  512
#define INTER 1536
#define NJOBS 16
#define EPS   1e-5f

typedef unsigned short u16;
typedef __attribute__((ext_vector_type(8))) short bf16x8;
typedef __attribute__((ext_vector_type(4))) float f32x4;
typedef __attribute__((ext_vector_type(4))) unsigned short u16x4;
typedef __attribute__((ext_vector_type(8))) unsigned short u16x8;

// ---------------- ws layout (total 34,603,088 floats = 138.4 MB, < 167.8 MB proven) ----------------
// float offsets:
#define HBF_OFF    0LL          // h bf16: u16[4,194,304] = 2,097,152 floats
#define AUX_OFF    2097152LL
#define RT_OFF     2097168LL    // 16 jobs * 4 floats
#define WB_OFF     2097232LL    // bf16 weights: u16[35,651,584] = 17,825,792 floats
#define PERJOB_OFF 19923024LL
#define JSZ        917504LL     // floats per job
#define JB16       1835008LL    // u16 per job
// u16 offsets within a job:
#define R1O   0LL               // qkv(786432) -> act(786432) -> out_e(524288), serially reused
#define HSBO  786432LL          // hs bf16 512x512
#define HS2BO 1048576LL         // hs2 bf16 512x512
#define HS3BO 1310720LL         // hs3 bf16 512x512
#define CTXBO 1572864LL         // attn ctx bf16 512x512
// u16 offsets within WB:
#define DWB 0LL
#define QWB 4194304LL
#define OWB 10485760LL
#define GUB 12582912LL
#define MDB 25165824LL
#define UWB 31457280LL

struct Job { int b; int e; float w; float pad; };

// ---------------- helpers ----------------
static __device__ __forceinline__ u16 f2b(float x) {
  unsigned u = __float_as_uint(x);
  unsigned r = (u + 0x7fffu + ((u >> 16) & 1u)) >> 16;
  return (u16)r;
}
static __device__ __forceinline__ float b2f(u16 x) {
  return __uint_as_float(((unsigned)x) << 16);
}
static __device__ __forceinline__ void gload_lds16(const void* g, void* l) {
  __builtin_amdgcn_global_load_lds(
      (const __attribute__((address_space(1))) unsigned int*)g,
      (__attribute__((address_space(3))) unsigned int*)l, 16, 0, 0);
}
static __device__ __forceinline__ float waveRedSum(float v) {
#pragma unroll
  for (int off = 32; off > 0; off >>= 1) v += __shfl_down(v, off, 64);
  return v;
}
static __device__ __forceinline__ float blockRedSum256(float v, float* buf) {
  v = waveRedSum(v);
  int wv = threadIdx.x >> 6;
  if ((threadIdx.x & 63) == 0) buf[wv] = v;
  __syncthreads();
  float r = buf[0] + buf[1] + buf[2] + buf[3];
  __syncthreads();
  return r;
}

// ---------------- hbf = bf16(hidden + injection) ----------------
__global__ __launch_bounds__(256) void k_add(const float* __restrict__ a,
                                             const float* __restrict__ b,
                                             u16* __restrict__ hbf) {
  long long i = ((long long)blockIdx.x * 256 + threadIdx.x) * 8;
  float4 x0 = *(const float4*)(a + i);
  float4 x1 = *(const float4*)(a + i + 4);
  float4 y0 = *(const float4*)(b + i);
  float4 y1 = *(const float4*)(b + i + 4);
  u16x8 o;
  o[0] = f2b(x0.x + y0.x); o[1] = f2b(x0.y + y0.y);
  o[2] = f2b(x0.z + y0.z); o[3] = f2b(x0.w + y0.w);
  o[4] = f2b(x1.x + y1.x); o[5] = f2b(x1.y + y1.y);
  o[6] = f2b(x1.z + y1.z); o[7] = f2b(x1.w + y1.w);
  *(u16x8*)(hbf + i) = o;
}

// ---------------- f32 -> bf16 (8 elems/thread) ----------------
__global__ __launch_bounds__(256) void k_f2b(const float* __restrict__ src, u16* __restrict__ dst) {
  long long i = ((long long)blockIdx.x * 256 + threadIdx.x) * 8;
  float4 a = *(const float4*)(src + i);
  float4 b = *(const float4*)(src + i + 4);
  u16x8 o;
  o[0] = f2b(a.x); o[1] = f2b(a.y); o[2] = f2b(a.z); o[3] = f2b(a.w);
  o[4] = f2b(b.x); o[5] = f2b(b.y); o[6] = f2b(b.z); o[7] = f2b(b.w);
  *(u16x8*)(dst + i) = o;
}

// ---------------- routing (reads hidden+inj rows s=0 directly, f32) ----------------
__global__ void k_routing(const float* __restrict__ hid, const float* __restrict__ inj,
                          const float* __restrict__ gate_w, float* __restrict__ ws) {
  __shared__ float lg[64];
  int t = threadIdx.x;
  {
    int b = t >> 3, e = t & 7;
    const float* hr = hid + (long long)b * (S_ * H_);
    const float* ir = inj + (long long)b * (S_ * H_);
    const float* g = gate_w + (long long)e * H_;
    float s = 0.f;
    for (int k = 0; k < H_; k++) s += (hr[k] + ir[k]) * g[k];
    lg[t] = s;
  }
  __syncthreads();
  if (t == 0) {
    Job* rt = (Job*)(ws + RT_OFF);
    float importance[E_] = {0};
    float load[E_] = {0};
    for (int b = 0; b < B_; b++) {
      float mx = lg[b * 8];
      for (int e = 1; e < E_; e++) mx = fmaxf(mx, lg[b * 8 + e]);
      float pr[E_]; float sum = 0.f;
      for (int e = 0; e < E_; e++) { pr[e] = expf(lg[b * 8 + e] - mx); sum += pr[e]; }
      for (int e = 0; e < E_; e++) { pr[e] /= sum; importance[e] += pr[e] * (1.0f / B_); }
      int i1 = 0;
      for (int e = 1; e < E_; e++) if (pr[e] > pr[i1]) i1 = e;
      int i2 = -1;
      for (int e = 0; e < E_; e++) if (e != i1 && (i2 < 0 || pr[e] > pr[i2])) i2 = e;
      float denom = pr[i1] + pr[i2];
      if (denom < 1e-8f) denom = 1e-8f;
      Job j1; j1.b = b; j1.e = i1; j1.w = pr[i1] / denom; j1.pad = 0.f;
      Job j2; j2.b = b; j2.e = i2; j2.w = pr[i2] / denom; j2.pad = 0.f;
      rt[2 * b + 0] = j1;
      rt[2 * b + 1] = j2;
      load[i1] += 1.0f / (B_ * 2);
      load[i2] += 1.0f / (B_ * 2);
    }
    float aux = 0.f;
    for (int e = 0; e < E_; e++) aux += (float)E_ * importance[e] * load[e];
    ws[AUX_OFF] = aux;
  }
}

// ---------------- bf16 MFMA NT GEMM, bf16 out ----------------
// C[m,n] = sum_k A[m,k]*W[n,k] (+ epilogue). BK=32, BN=128, 4 waves.
// LDS: [rows][32 bf16], 16B-chunk XOR swizzle (chunk ^= (row>>1)&3) applied on
// the pre-swizzled GLOBAL source; LDS dest linear (rule #21); reads swizzled.
template <int BM, int EPI>   // EPI: 0 plain, 1 +b2f(Add), 2 *jb.w
__global__ __launch_bounds__(256) void k_mfma(
    const u16* __restrict__ Abase, long long aStride, int aByB, int lda,
    const u16* __restrict__ Wbase, long long wStride, int ldb,
    u16* __restrict__ Cbase, long long cStride, int ldc,
    const u16* __restrict__ AddBase, long long addStride, int ldadd,
    const Job* __restrict__ rt, int Kd) {
  constexpr int BN = 128;
  constexpr int WAVES_N = (BM == 128) ? 2 : 4;
  constexpr int WN = BN / WAVES_N;
  constexpr int MI = 4;
  constexpr int NI = WN / 16;

  __shared__ __align__(16) char smem[(BM + BN) * 64];
  char* As = smem;
  char* Bs = smem + BM * 64;

  const int job = blockIdx.z;
  const Job jb = rt[job];
  const u16* A = Abase + (aByB ? (long long)jb.b : (long long)job) * aStride;
  const u16* W = Wbase + (long long)jb.e * wStride;

  const int t = threadIdx.x;
  const int l = t & 63, w = t >> 6;
  const int wr = w / WAVES_N, wc = w % WAVES_N;
  const int m0 = blockIdx.y * BM, n0 = blockIdx.x * BN;

  const int srow = (w << 4) + (l >> 2);                 // staged row
  const int scg = (l & 3) ^ ((l >> 3) & 3);             // pre-swizzled global chunk
  const int cA = (((l >> 4) ^ ((l >> 1) & 3)) & 3) << 4; // swizzled read chunk

  f32x4 acc[MI][NI] = {};

  for (int k0 = 0; k0 < Kd; k0 += 32) {
#pragma unroll
    for (int i = 0; i < BM / 64; ++i)
      gload_lds16(A + (long long)(m0 + i * 64 + srow) * lda + k0 + scg * 8,
                  As + i * 4096 + (w << 10));
#pragma unroll
    for (int i = 0; i < 2; ++i)
      gload_lds16(W + (long long)(n0 + i * 64 + srow) * ldb + k0 + scg * 8,
                  Bs + i * 4096 + (w << 10));
    __syncthreads();

    bf16x8 af[MI], bfr[NI];
#pragma unroll
    for (int mi = 0; mi < MI; ++mi)
      af[mi] = *(const bf16x8*)(As + ((wr * 64 + mi * 16 + (l & 15)) << 6) + cA);
#pragma unroll
    for (int ni = 0; ni < NI; ++ni)
      bfr[ni] = *(const bf16x8*)(Bs + ((wc * WN + ni * 16 + (l & 15)) << 6) + cA);
#pragma unroll
    for (int mi = 0; mi < MI; ++mi)
#pragma unroll
      for (int ni = 0; ni < NI; ++ni)
        acc[mi][ni] = __builtin_amdgcn_mfma_f32_16x16x32_bf16(af[mi], bfr[ni], acc[mi][ni], 0, 0, 0);
    __syncthreads();
  }

  u16* C = Cbase + (long long)job * cStride;
  const u16* Add = (EPI == 1) ? (AddBase + (long long)job * addStride) : nullptr;

#pragma unroll
  for (int mi = 0; mi < MI; ++mi) {
#pragma unroll
    for (int r = 0; r < 4; ++r) {
      int m = m0 + wr * 64 + mi * 16 + ((l >> 4) << 2) + r;
#pragma unroll
      for (int ni = 0; ni < NI; ++ni) {
        int n = n0 + wc * WN + ni * 16 + (l & 15);
        float v = acc[mi][ni][r];
        if (EPI == 1) v += b2f(Add[(long long)m * ldadd + n]);
        if (EPI == 2) v *= jb.w;
        C[(long long)m * ldc + n] = f2b(v);
      }
    }
  }
}

// ---------------- fused gate_up GEMM + SiLU: act[m,n] = silu(g)*u ----------------
// BM=64, BN=128. Block computes gate tile (rows n0..) AND up tile (rows 1536+n0..).
__global__ __launch_bounds__(256) void k_mfma_glu(
    const u16* __restrict__ Abase, long long aStride, int lda,
    const u16* __restrict__ Wbase, long long wStride, int ldb,
    u16* __restrict__ Cbase, long long cStride, int ldc,
    const Job* __restrict__ rt, int Kd) {
  __shared__ __align__(16) char smem[(64 + 128 + 128) * 64];
  char* As = smem;
  char* Bg = smem + 64 * 64;
  char* Bu = smem + (64 + 128) * 64;

  const int job = blockIdx.z;
  const Job jb = rt[job];
  const u16* A = Abase + (long long)job * aStride;
  const u16* W = Wbase + (long long)jb.e * wStride;

  const int t = threadIdx.x;
  const int l = t & 63, w = t >> 6;
  const int wc = w;                      // WAVES_N=4, wr=0
  const int m0 = blockIdx.y * 64, n0 = blockIdx.x * 128;

  const int srow = (w << 4) + (l >> 2);
  const int scg = (l & 3) ^ ((l >> 3) & 3);
  const int cA = (((l >> 4) ^ ((l >> 1) & 3)) & 3) << 4;

  f32x4 accg[4][2] = {};
  f32x4 accu[4][2] = {};

  for (int k0 = 0; k0 < Kd; k0 += 32) {
    gload_lds16(A + (long long)(m0 + srow) * lda + k0 + scg * 8, As + (w << 10));
#pragma unroll
    for (int i = 0; i < 2; ++i) {
      gload_lds16(W + (long long)(n0 + i * 64 + srow) * ldb + k0 + scg * 8,
                  Bg + i * 4096 + (w << 10));
      gload_lds16(W + (long long)(1536 + n0 + i * 64 + srow) * ldb + k0 + scg * 8,
                  Bu + i * 4096 + (w << 10));
    }
    __syncthreads();

    bf16x8 af[4], bg[2], bu[2];
#pragma unroll
    for (int mi = 0; mi < 4; ++mi)
      af[mi] = *(const bf16x8*)(As + ((mi * 16 + (l & 15)) << 6) + cA);
#pragma unroll
    for (int ni = 0; ni < 2; ++ni) {
      bg[ni] = *(const bf16x8*)(Bg + ((wc * 32 + ni * 16 + (l & 15)) << 6) + cA);
      bu[ni] = *(const bf16x8*)(Bu + ((wc * 32 + ni * 16 + (l & 15)) << 6) + cA);
    }
#pragma unroll
    for (int mi = 0; mi < 4; ++mi)
#pragma unroll
      for (int ni = 0; ni < 2; ++ni) {
        accg[mi][ni] = __builtin_amdgcn_mfma_f32_16x16x32_bf16(af[mi], bg[ni], accg[mi][ni], 0, 0, 0);
        accu[mi][ni] = __builtin_amdgcn_mfma_f32_16x16x32_bf16(af[mi], bu[ni], accu[mi][ni], 0, 0, 0);
      }
    __syncthreads();
  }

  u16* C = Cbase + (long long)job * cStride;
#pragma unroll
  for (int mi = 0; mi < 4; ++mi) {
#pragma unroll
    for (int r = 0; r < 4; ++r) {
      int m = m0 + mi * 16 + ((l >> 4) << 2) + r;
#pragma unroll
      for (int ni = 0; ni < 2; ++ni) {
        int n = n0 + wc * 32 + ni * 16 + (l & 15);
        float g = accg[mi][ni][r];
        float u = accu[mi][ni][r];
        C[(long long)m * ldc + n] = f2b(g / (1.f + __expf(-g)) * u);
      }
    }
  }
}

// ---------------- RoPE in-place on bf16 qkv ----------------
__global__ __launch_bounds__(256) void k_rope(u16* __restrict__ qkvBase,
                                              const float* __restrict__ cosT,
                                              const float* __restrict__ sinT) {
  int i = blockIdx.x;
  int job = blockIdx.y;
  u16* qkv = qkvBase + (long long)job * JB16;
  int t = threadIdx.x;
  int head = t >> 5, d = t & 31;
  int col = head * 64 + d;
  float c1 = cosT[i * 64 + d], c2 = cosT[i * 64 + d + 32];
  float s1 = sinT[i * 64 + d], s2 = sinT[i * 64 + d + 32];
  u16* row = qkv + (long long)i * 1536;
  float x1 = b2f(row[col]), x2 = b2f(row[col + 32]);
  row[col] = f2b(x1 * c1 - x2 * s1);
  row[col + 32] = f2b(x2 * c2 + x1 * s2);
  float y1 = b2f(row[512 + col]), y2 = b2f(row[512 + col + 32]);
  row[512 + col] = f2b(y1 * c1 - y2 * s1);
  row[512 + col + 32] = f2b(y2 * c2 + y1 * s2);
}

// ---------------- flash attention (fp32 compute, bf16 in/out) ----------------
__global__ __launch_bounds__(256) void k_attn2(const u16* __restrict__ qkvBase,
                                               u16* __restrict__ ctxBase) {
  const int qt = blockIdx.x;
  const int head = blockIdx.y;
  const int job = blockIdx.z;
  const u16* qkv = qkvBase + (long long)job * JB16;
  u16* ctx = ctxBase + (long long)job * JB16;
  const int t = threadIdx.x;
  const int tx = t & 15, ty = t >> 4;
  const int q0 = qt * 64;
  const u16* hb = qkv + head * 64;

  __shared__ float Qs[64][65];
  __shared__ float Ks[64][65];
  __shared__ float Vs[64][65];
  __shared__ float Ps[64][66];

#pragma unroll
  for (int c = 0; c < 4; c++) {
    int qi = c * 256 + t;
    int m = qi >> 4, d4 = (qi & 15) << 2;
    u16x4 v = *(const u16x4*)(hb + (long long)(q0 + m) * 1536 + d4);
    Qs[d4 + 0][m] = b2f(v[0]); Qs[d4 + 1][m] = b2f(v[1]);
    Qs[d4 + 2][m] = b2f(v[2]); Qs[d4 + 3][m] = b2f(v[3]);
  }

  float acc[4][4] = {};
  float mrun[4] = {-1e30f, -1e30f, -1e30f, -1e30f};
  float lrun[4] = {0.f, 0.f, 0.f, 0.f};

  for (int kt = 0; kt < 8; kt++) {
    const int k0 = kt * 64;
#pragma unroll
    for (int c = 0; c < 4; c++) {
      int qi = c * 256 + t;
      int m = qi >> 4, d4 = (qi & 15) << 2;
      const u16* rb = hb + (long long)(k0 + m) * 1536;
      u16x4 kv = *(const u16x4*)(rb + 512 + d4);
      u16x4 vv = *(const u16x4*)(rb + 1024 + d4);
      Ks[d4 + 0][m] = b2f(kv[0]); Ks[d4 + 1][m] = b2f(kv[1]);
      Ks[d4 + 2][m] = b2f(kv[2]); Ks[d4 + 3][m] = b2f(kv[3]);
      Vs[m][d4 + 0] = b2f(vv[0]); Vs[m][d4 + 1] = b2f(vv[1]);
      Vs[m][d4 + 2] = b2f(vv[2]); Vs[m][d4 + 3] = b2f(vv[3]);
    }
    __syncthreads();

    float s[4][4] = {};
#pragma unroll 4
    for (int d = 0; d < 64; d++) {
      float a0 = Qs[d][ty * 4 + 0], a1 = Qs[d][ty * 4 + 1],
            a2 = Qs[d][ty * 4 + 2], a3 = Qs[d][ty * 4 + 3];
      float b0 = Ks[d][tx * 4 + 0], b1 = Ks[d][tx * 4 + 1],
            b2 = Ks[d][tx * 4 + 2], b3 = Ks[d][tx * 4 + 3];
      s[0][0] = fmaf(a0, b0, s[0][0]); s[0][1] = fmaf(a0, b1, s[0][1]);
      s[0][2] = fmaf(a0, b2, s[0][2]); s[0][3] = fmaf(a0, b3, s[0][3]);
      s[1][0] = fmaf(a1, b0, s[1][0]); s[1][1] = fmaf(a1, b1, s[1][1]);
      s[1][2] = fmaf(a1, b2, s[1][2]); s[1][3] = fmaf(a1, b3, s[1][3]);
      s[2][0] = fmaf(a2, b0, s[2][0]); s[2][1] = fmaf(a2, b1, s[2][1]);
      s[2][2] = fmaf(a2, b2, s[2][2]); s[2][3] = fmaf(a2, b3, s[2][3]);
      s[3][0] = fmaf(a3, b0, s[3][0]); s[3][1] = fmaf(a3, b1, s[3][1]);
      s[3][2] = fmaf(a3, b2, s[3][2]); s[3][3] = fmaf(a3, b3, s[3][3]);
    }

#pragma unroll
    for (int i = 0; i < 4; i++) {
      float rm = fmaxf(fmaxf(s[i][0], s[i][1]), fmaxf(s[i][2], s[i][3])) * 0.125f;
#pragma unroll
      for (int off = 8; off > 0; off >>= 1) rm = fmaxf(rm, __shfl_xor(rm, off, 16));
      float mnew = fmaxf(mrun[i], rm);
      float sc = __expf(mrun[i] - mnew);
      float rs = 0.f;
#pragma unroll
      for (int j = 0; j < 4; j++) {
        float p = __expf(fmaf(s[i][j], 0.125f, -mnew));
        s[i][j] = p; rs += p;
      }
#pragma unroll
      for (int off = 8; off > 0; off >>= 1) rs += __shfl_xor(rs, off, 16);
      lrun[i] = lrun[i] * sc + rs;
      mrun[i] = mnew;
#pragma unroll
      for (int j = 0; j < 4; j++) acc[i][j] *= sc;
      Ps[ty * 4 + i][tx * 4 + 0] = s[i][0];
      Ps[ty * 4 + i][tx * 4 + 1] = s[i][1];
      Ps[ty * 4 + i][tx * 4 + 2] = s[i][2];
      Ps[ty * 4 + i][tx * 4 + 3] = s[i][3];
    }
    __syncthreads();

#pragma unroll 4
    for (int kk = 0; kk < 64; kk++) {
      float a0 = Ps[ty * 4 + 0][kk], a1 = Ps[ty * 4 + 1][kk],
            a2 = Ps[ty * 4 + 2][kk], a3 = Ps[ty * 4 + 3][kk];
      float b0 = Vs[kk][tx * 4 + 0], b1 = Vs[kk][tx * 4 + 1],
            b2 = Vs[kk][tx * 4 + 2], b3 = Vs[kk][tx * 4 + 3];
      acc[0][0] = fmaf(a0, b0, acc[0][0]); acc[0][1] = fmaf(a0, b1, acc[0][1]);
      acc[0][2] = fmaf(a0, b2, acc[0][2]); acc[0][3] = fmaf(a0, b3, acc[0][3]);
      acc[1][0] = fmaf(a1, b0, acc[1][0]); acc[1][1] = fmaf(a1, b1, acc[1][1]);
      acc[1][2] = fmaf(a1, b2, acc[1][2]); acc[1][3] = fmaf(a1, b3, acc[1][3]);
      acc[2][0] = fmaf(a2, b0, acc[2][0]); acc[2][1] = fmaf(a2, b1, acc[2][1]);
      acc[2][2] = fmaf(a2, b2, acc[2][2]); acc[2][3] = fmaf(a2, b3, acc[2][3]);
      acc[3][0] = fmaf(a3, b0, acc[3][0]); acc[3][1] = fmaf(a3, b1, acc[3][1]);
      acc[3][2] = fmaf(a3, b2, acc[3][2]); acc[3][3] = fmaf(a3, b3, acc[3][3]);
    }
    __syncthreads();
  }

#pragma unroll
  for (int i = 0; i < 4; i++) {
    float inv = 1.0f / lrun[i];
#pragma unroll
    for (int j = 0; j < 4; j++)
      ctx[(long long)(q0 + ty * 4 + i) * 512 + head * 64 + tx * 4 + j] = f2b(acc[i][j] * inv);
  }
}

// ---------------- RMSNorm rows of 512: bf16 in-place ----------------
__global__ __launch_bounds__(256) void k_rms512(u16* __restrict__ base, long long strideB) {
  u16* x = base + (long long)blockIdx.y * strideB + (long long)blockIdx.x * 512;
  int t = threadIdx.x;
  __shared__ float buf[4];
  float a0 = b2f(x[t]), a1 = b2f(x[t + 256]);
  float ss = blockRedSum256(a0 * a0 + a1 * a1, buf);
  float r = rsqrtf(ss * (1.0f / 512.0f) + EPS);
  x[t] = f2b(a0 * r);
  x[t + 256] = f2b(a1 * r);
}

// ---------------- final: out = rms_norm(hidden+inj + oute1 + oute2), plus aux ----------------
__global__ __launch_bounds__(256) void k_final(const float* __restrict__ hid,
                                               const float* __restrict__ inj,
                                               const float* __restrict__ ws,
                                               const u16* __restrict__ jobsBase,
                                               float* __restrict__ out, int auxIdx) {
  int row = blockIdx.x;
  int b = row >> 9;
  int s = row & 511;
  const float* hr = hid + (long long)row * H_;
  const float* ir = inj + (long long)row * H_;
  const u16* o1 = jobsBase + (long long)(2 * b) * JB16 + R1O + (long long)s * H_;
  const u16* o2 = jobsBase + (long long)(2 * b + 1) * JB16 + R1O + (long long)s * H_;
  int t = threadIdx.x;
  __shared__ float buf[4];
  float v[4];
  float ss = 0.f;
#pragma unroll
  for (int c = 0; c < 4; c++) {
    int d = t + c * 256;
    v[c] = hr[d] + ir[d] + b2f(o1[d]) + b2f(o2[d]);
    ss += v[c] * v[c];
  }
  ss = blockRedSum256(ss, buf);
  float r = rsqrtf(ss * (1.0f / (float)H_) + EPS);
#pragma unroll
  for (int c = 0; c < 4; c++)
    out[(long long)row * H_ + t + c * 256] = v[c] * r;
  if (row == 0 && t == 0) out[auxIdx] = ws[AUX_OFF];
}

// ---------------- launch ----------------
extern "C" void kernel_launch(void* const* d_in, const int* in_sizes, int n_in,
                              void* d_out, int out_size, void* d_ws, size_t ws_size,
                              hipStream_t stream) {
  const float* hidden = (const float*)d_in[0];
  const float* inj    = (const float*)d_in[1];
  const float* cosT   = (const float*)d_in[2];
  const float* sinT   = (const float*)d_in[3];
  const float* gate_w = (const float*)d_in[4];
  const float* down_w = (const float*)d_in[5];
  const float* up_w   = (const float*)d_in[6];
  const float* qkv_w  = (const float*)d_in[7];
  const float* o_w    = (const float*)d_in[8];
  const float* gup_w  = (const float*)d_in[9];
  const float* mdw    = (const float*)d_in[10];
  float* out = (float*)d_out;
  float* ws  = (float*)d_ws;

  u16* hbf = (u16*)(ws + HBF_OFF);
  u16* wb  = (u16*)(ws + WB_OFF);
  const Job* rt = (const Job*)(ws + RT_OFF);
  u16* jobs = (u16*)(ws + PERJOB_OFF);

  u16* r1B   = jobs + R1O;     // qkv / act / out_e
  u16* hsB   = jobs + HSBO;
  u16* hs2B  = jobs + HS2BO;
  u16* hs3B  = jobs + HS3BO;
  u16* ctxB  = jobs + CTXBO;

  k_add<<<2048, 256, 0, stream>>>(hidden, inj, hbf);
  k_routing<<<1, 64, 0, stream>>>(hidden, inj, gate_w, ws);

  // weight conversions (f32 -> bf16)
  k_f2b<<<2048, 256, 0, stream>>>(down_w, wb + DWB);
  k_f2b<<<3072, 256, 0, stream>>>(qkv_w,  wb + QWB);
  k_f2b<<<1024, 256, 0, stream>>>(o_w,    wb + OWB);
  k_f2b<<<6144, 256, 0, stream>>>(gup_w,  wb + GUB);
  k_f2b<<<3072, 256, 0, stream>>>(mdw,    wb + MDB);
  k_f2b<<<2048, 256, 0, stream>>>(up_w,   wb + UWB);

  // G1: hs = h[b] @ down_w[e].T   (512x512, K=1024) -> hsB
  k_mfma<64, 0><<<dim3(4, 8, NJOBS), 256, 0, stream>>>(
      hbf, (long long)S_ * H_, 1, H_,
      wb + DWB, (long long)HSUB * H_, H_,
      hsB, JB16, HSUB, nullptr, 0, 0, rt, H_);

  // G2: qkv = hs @ qkv_w[e].T     (512x1536, K=512) -> r1B (bf16)
  k_mfma<128, 0><<<dim3(12, 4, NJOBS), 256, 0, stream>>>(
      hsB, JB16, 0, HSUB,
      wb + QWB, (long long)3 * NH * HD * HSUB, HSUB,
      r1B, JB16, 1536, nullptr, 0, 0, rt, HSUB);

  k_rope<<<dim3(S_, NJOBS), 256, 0, stream>>>(r1B, cosT, sinT);
  k_attn2<<<dim3(8, NH, NJOBS), 256, 0, stream>>>(r1B, ctxB);

  // G3: hs2pre = hs + ctx @ o_w[e].T (512x512, K=512) -> hs2B, then rms in place
  k_mfma<64, 1><<<dim3(4, 8, NJOBS), 256, 0, stream>>>(
      ctxB, JB16, 0, HSUB,
      wb + OWB, (long long)HSUB * HSUB, HSUB,
      hs2B, JB16, HSUB, hsB, JB16, HSUB, rt, HSUB);
  k_rms512<<<dim3(S_, NJOBS), 256, 0, stream>>>(hs2B, JB16);

  // G4: act = silu(hs2@gate.T) * (hs2@up.T)  (512x1536, K=512) -> r1B
  k_mfma_glu<<<dim3(12, 8, NJOBS), 256, 0, stream>>>(
      hs2B, JB16, HSUB,
      wb + GUB, (long long)2 * INTER * HSUB, HSUB,
      r1B, JB16, 1536, rt, HSUB);

  // G5: hs3pre = hs2 + act @ mdw[e].T (512x512, K=1536) -> hs3B, rms in place
  k_mfma<64, 1><<<dim3(4, 8, NJOBS), 256, 0, stream>>>(
      r1B, JB16, 0, INTER,
      wb + MDB, (long long)HSUB * INTER, INTER,
      hs3B, JB16, HSUB, hs2B, JB16, HSUB, rt, INTER);
  k_rms512<<<dim3(S_, NJOBS), 256, 0, stream>>>(hs3B, JB16);

  // G6: out_e = (hs3 @ up_w[e].T) * jb.w (512x1024, K=512) -> r1B (bf16)
  k_mfma<128, 2><<<dim3(8, 4, NJOBS), 256, 0, stream>>>(
      hs3B, JB16, 0, HSUB,
      wb + UWB, (long long)H_ * HSUB, HSUB,
      r1B, JB16, H_, nullptr, 0, 0, rt, HSUB);

  k_final<<<B_ * S_, 256, 0, stream>>>(hidden, inj, ws, jobs, out, out_size - 1);
}

// Round 10
// 490.232 us; speedup vs baseline: 12.5427x; 1.2753x over previous
//
#include <hip/hip_runtime.h>
#include <hip/hip_bf16.h>

// ---------------- problem constants ----------------
#define B_    8
#define S_    512
#define H_    1024
#define E_    8
#define NH    8
#define HD    64
#define HSUB  512
#define INTER 1536
#define NJOBS 16
#define EPS   1e-5f

typedef unsigned short u16;
typedef __attribute__((ext_vector_type(8))) short bf16x8;
typedef __attribute__((ext_vector_type(4))) float f32x4;
typedef __attribute__((ext_vector_type(4))) unsigned short u16x4;
typedef __attribute__((ext_vector_type(8))) unsigned short u16x8;

// ---------------- ws layout (138.4 MB total, proven-safe envelope) ----------------
#define HBF_OFF    0LL
#define AUX_OFF    2097152LL
#define RT_OFF     2097168LL
#define WB_OFF     2097232LL
#define PERJOB_OFF 19923024LL
#define JB16       1835008LL    // u16 per job
// u16 offsets within a job:
#define R1O   0LL               // qk(512x1024) -> act(512x1536) -> out_e(512x1024)
#define VTO   524288LL          // vT (512 d x 512 seq), aliases upper R1 third
#define HSBO  786432LL
#define HS2BO 1048576LL
#define HS3BO 1310720LL
#define CTXBO 1572864LL
// u16 offsets within WB:
#define DWB 0LL
#define QWB 4194304LL
#define OWB 10485760LL
#define GUB 12582912LL
#define MDB 25165824LL
#define UWB 31457280LL

struct Job { int b; int e; float w; float pad; };

// ---------------- helpers ----------------
static __device__ __forceinline__ u16 f2b(float x) {
  unsigned u = __float_as_uint(x);
  unsigned r = (u + 0x7fffu + ((u >> 16) & 1u)) >> 16;
  return (u16)r;
}
static __device__ __forceinline__ float b2f(u16 x) {
  return __uint_as_float(((unsigned)x) << 16);
}
static __device__ __forceinline__ void gload_lds16(const void* g, void* l) {
  __builtin_amdgcn_global_load_lds(
      (const __attribute__((address_space(1))) unsigned int*)g,
      (__attribute__((address_space(3))) unsigned int*)l, 16, 0, 0);
}
static __device__ __forceinline__ float waveRedSum(float v) {
#pragma unroll
  for (int off = 32; off > 0; off >>= 1) v += __shfl_down(v, off, 64);
  return v;
}
static __device__ __forceinline__ float blockRedSum256(float v, float* buf) {
  v = waveRedSum(v);
  int wv = threadIdx.x >> 6;
  if ((threadIdx.x & 63) == 0) buf[wv] = v;
  __syncthreads();
  float r = buf[0] + buf[1] + buf[2] + buf[3];
  __syncthreads();
  return r;
}
// fragment read from a [64][64]-bf16 tile, 128B rows, chunk-XOR-swizzled by row&7
static __device__ __forceinline__ bf16x8 frag64(const char* lds, int rbase, int s, int l) {
  int row = rbase + (l & 15);
  int c = ((s << 2) + (l >> 4)) ^ (row & 7);
  return *(const bf16x8*)(lds + row * 128 + c * 16);
}

// ---------------- hbf = bf16(hidden + injection) ----------------
__global__ __launch_bounds__(256) void k_add(const float* __restrict__ a,
                                             const float* __restrict__ b,
                                             u16* __restrict__ hbf) {
  long long i = ((long long)blockIdx.x * 256 + threadIdx.x) * 8;
  float4 x0 = *(const float4*)(a + i);
  float4 x1 = *(const float4*)(a + i + 4);
  float4 y0 = *(const float4*)(b + i);
  float4 y1 = *(const float4*)(b + i + 4);
  u16x8 o;
  o[0] = f2b(x0.x + y0.x); o[1] = f2b(x0.y + y0.y);
  o[2] = f2b(x0.z + y0.z); o[3] = f2b(x0.w + y0.w);
  o[4] = f2b(x1.x + y1.x); o[5] = f2b(x1.y + y1.y);
  o[6] = f2b(x1.z + y1.z); o[7] = f2b(x1.w + y1.w);
  *(u16x8*)(hbf + i) = o;
}

// ---------------- f32 -> bf16 ----------------
__global__ __launch_bounds__(256) void k_f2b(const float* __restrict__ src, u16* __restrict__ dst) {
  long long i = ((long long)blockIdx.x * 256 + threadIdx.x) * 8;
  float4 a = *(const float4*)(src + i);
  float4 b = *(const float4*)(src + i + 4);
  u16x8 o;
  o[0] = f2b(a.x); o[1] = f2b(a.y); o[2] = f2b(a.z); o[3] = f2b(a.w);
  o[4] = f2b(b.x); o[5] = f2b(b.y); o[6] = f2b(b.z); o[7] = f2b(b.w);
  *(u16x8*)(dst + i) = o;
}

// ---------------- routing ----------------
__global__ void k_routing(const float* __restrict__ hid, const float* __restrict__ inj,
                          const float* __restrict__ gate_w, float* __restrict__ ws) {
  __shared__ float lg[64];
  int t = threadIdx.x;
  {
    int b = t >> 3, e = t & 7;
    const float* hr = hid + (long long)b * (S_ * H_);
    const float* ir = inj + (long long)b * (S_ * H_);
    const float* g = gate_w + (long long)e * H_;
    float s = 0.f;
    for (int k = 0; k < H_; k++) s += (hr[k] + ir[k]) * g[k];
    lg[t] = s;
  }
  __syncthreads();
  if (t == 0) {
    Job* rt = (Job*)(ws + RT_OFF);
    float importance[E_] = {0};
    float load[E_] = {0};
    for (int b = 0; b < B_; b++) {
      float mx = lg[b * 8];
      for (int e = 1; e < E_; e++) mx = fmaxf(mx, lg[b * 8 + e]);
      float pr[E_]; float sum = 0.f;
      for (int e = 0; e < E_; e++) { pr[e] = expf(lg[b * 8 + e] - mx); sum += pr[e]; }
      for (int e = 0; e < E_; e++) { pr[e] /= sum; importance[e] += pr[e] * (1.0f / B_); }
      int i1 = 0;
      for (int e = 1; e < E_; e++) if (pr[e] > pr[i1]) i1 = e;
      int i2 = -1;
      for (int e = 0; e < E_; e++) if (e != i1 && (i2 < 0 || pr[e] > pr[i2])) i2 = e;
      float denom = pr[i1] + pr[i2];
      if (denom < 1e-8f) denom = 1e-8f;
      Job j1; j1.b = b; j1.e = i1; j1.w = pr[i1] / denom; j1.pad = 0.f;
      Job j2; j2.b = b; j2.e = i2; j2.w = pr[i2] / denom; j2.pad = 0.f;
      rt[2 * b + 0] = j1;
      rt[2 * b + 1] = j2;
      load[i1] += 1.0f / (B_ * 2);
      load[i2] += 1.0f / (B_ * 2);
    }
    float aux = 0.f;
    for (int e = 0; e < E_; e++) aux += (float)E_ * importance[e] * load[e];
    ws[AUX_OFF] = aux;
  }
}

// ---------------- bf16 MFMA NT GEMM (validated structure) ----------------
template <int BM, int EPI>   // EPI: 0 plain, 1 +b2f(Add), 2 *jb.w
__global__ __launch_bounds__(256) void k_mfma(
    const u16* __restrict__ Abase, long long aStride, int aByB, int lda,
    const u16* __restrict__ Wbase, long long wStride, int ldb,
    u16* __restrict__ Cbase, long long cStride, int ldc,
    const u16* __restrict__ AddBase, long long addStride, int ldadd,
    const Job* __restrict__ rt, int Kd) {
  constexpr int BN = 128;
  constexpr int WAVES_N = (BM == 128) ? 2 : 4;
  constexpr int WN = BN / WAVES_N;
  constexpr int MI = 4;
  constexpr int NI = WN / 16;

  __shared__ __align__(16) char smem[(BM + BN) * 64];
  char* As = smem;
  char* Bs = smem + BM * 64;

  const int job = blockIdx.z;
  const Job jb = rt[job];
  const u16* A = Abase + (aByB ? (long long)jb.b : (long long)job) * aStride;
  const u16* W = Wbase + (long long)jb.e * wStride;

  const int t = threadIdx.x;
  const int l = t & 63, w = t >> 6;
  const int wr = w / WAVES_N, wc = w % WAVES_N;
  const int m0 = blockIdx.y * BM, n0 = blockIdx.x * BN;

  const int srow = (w << 4) + (l >> 2);
  const int scg = (l & 3) ^ ((l >> 3) & 3);
  const int cA = (((l >> 4) ^ ((l >> 1) & 3)) & 3) << 4;

  f32x4 acc[MI][NI] = {};

  for (int k0 = 0; k0 < Kd; k0 += 32) {
#pragma unroll
    for (int i = 0; i < BM / 64; ++i)
      gload_lds16(A + (long long)(m0 + i * 64 + srow) * lda + k0 + scg * 8,
                  As + i * 4096 + (w << 10));
#pragma unroll
    for (int i = 0; i < 2; ++i)
      gload_lds16(W + (long long)(n0 + i * 64 + srow) * ldb + k0 + scg * 8,
                  Bs + i * 4096 + (w << 10));
    __syncthreads();

    bf16x8 af[MI], bfr[NI];
#pragma unroll
    for (int mi = 0; mi < MI; ++mi)
      af[mi] = *(const bf16x8*)(As + ((wr * 64 + mi * 16 + (l & 15)) << 6) + cA);
#pragma unroll
    for (int ni = 0; ni < NI; ++ni)
      bfr[ni] = *(const bf16x8*)(Bs + ((wc * WN + ni * 16 + (l & 15)) << 6) + cA);
#pragma unroll
    for (int mi = 0; mi < MI; ++mi)
#pragma unroll
      for (int ni = 0; ni < NI; ++ni)
        acc[mi][ni] = __builtin_amdgcn_mfma_f32_16x16x32_bf16(af[mi], bfr[ni], acc[mi][ni], 0, 0, 0);
    __syncthreads();
  }

  u16* C = Cbase + (long long)job * cStride;
  const u16* Add = (EPI == 1) ? (AddBase + (long long)job * addStride) : nullptr;

#pragma unroll
  for (int mi = 0; mi < MI; ++mi) {
#pragma unroll
    for (int r = 0; r < 4; ++r) {
      int m = m0 + wr * 64 + mi * 16 + ((l >> 4) << 2) + r;
#pragma unroll
      for (int ni = 0; ni < NI; ++ni) {
        int n = n0 + wc * WN + ni * 16 + (l & 15);
        float v = acc[mi][ni][r];
        if (EPI == 1) v += b2f(Add[(long long)m * ldadd + n]);
        if (EPI == 2) v *= jb.w;
        C[(long long)m * ldc + n] = f2b(v);
      }
    }
  }
}

// ---------------- QKV GEMM: q,k -> qk[512][1024]; v -> vT[512 d][512 seq] ----------------
__global__ __launch_bounds__(256) void k_mfma_qkv(
    const u16* __restrict__ Abase, long long aStride, int lda,
    const u16* __restrict__ Wbase, long long wStride, int ldb,
    u16* __restrict__ qkB, u16* __restrict__ vtB, long long cStride,
    const Job* __restrict__ rt) {
  __shared__ __align__(16) char smem[256 * 64];
  char* As = smem;
  char* Bs = smem + 128 * 64;

  const int job = blockIdx.z;
  const Job jb = rt[job];
  const u16* A = Abase + (long long)job * aStride;
  const u16* W = Wbase + (long long)jb.e * wStride;

  const int t = threadIdx.x;
  const int l = t & 63, w = t >> 6;
  const int wr = w >> 1, wc = w & 1;
  const int m0 = blockIdx.y * 128, n0 = blockIdx.x * 128;

  const int srow = (w << 4) + (l >> 2);
  const int scg = (l & 3) ^ ((l >> 3) & 3);
  const int cA = (((l >> 4) ^ ((l >> 1) & 3)) & 3) << 4;

  f32x4 acc[4][4] = {};

  for (int k0 = 0; k0 < HSUB; k0 += 32) {
#pragma unroll
    for (int i = 0; i < 2; ++i)
      gload_lds16(A + (long long)(m0 + i * 64 + srow) * lda + k0 + scg * 8,
                  As + i * 4096 + (w << 10));
#pragma unroll
    for (int i = 0; i < 2; ++i)
      gload_lds16(W + (long long)(n0 + i * 64 + srow) * ldb + k0 + scg * 8,
                  Bs + i * 4096 + (w << 10));
    __syncthreads();

    bf16x8 af[4], bfr[4];
#pragma unroll
    for (int mi = 0; mi < 4; ++mi)
      af[mi] = *(const bf16x8*)(As + ((wr * 64 + mi * 16 + (l & 15)) << 6) + cA);
#pragma unroll
    for (int ni = 0; ni < 4; ++ni)
      bfr[ni] = *(const bf16x8*)(Bs + ((wc * 64 + ni * 16 + (l & 15)) << 6) + cA);
#pragma unroll
    for (int mi = 0; mi < 4; ++mi)
#pragma unroll
      for (int ni = 0; ni < 4; ++ni)
        acc[mi][ni] = __builtin_amdgcn_mfma_f32_16x16x32_bf16(af[mi], bfr[ni], acc[mi][ni], 0, 0, 0);
    __syncthreads();
  }

  if (n0 < 1024) {
    u16* C = qkB + (long long)job * cStride;
#pragma unroll
    for (int mi = 0; mi < 4; ++mi)
#pragma unroll
      for (int r = 0; r < 4; ++r) {
        int m = m0 + wr * 64 + mi * 16 + ((l >> 4) << 2) + r;
#pragma unroll
        for (int ni = 0; ni < 4; ++ni) {
          int n = n0 + wc * 64 + ni * 16 + (l & 15);
          C[(long long)m * 1024 + n] = f2b(acc[mi][ni][r]);
        }
      }
  } else {
    u16* VT = vtB + (long long)job * cStride;
#pragma unroll
    for (int mi = 0; mi < 4; ++mi) {
      int mb = m0 + wr * 64 + mi * 16 + ((l >> 4) << 2);
#pragma unroll
      for (int ni = 0; ni < 4; ++ni) {
        int d = n0 - 1024 + wc * 64 + ni * 16 + (l & 15);
        u16x4 o;
        o[0] = f2b(acc[mi][ni][0]); o[1] = f2b(acc[mi][ni][1]);
        o[2] = f2b(acc[mi][ni][2]); o[3] = f2b(acc[mi][ni][3]);
        *(u16x4*)(VT + (long long)d * 512 + mb) = o;
      }
    }
  }
}

// ---------------- fused gate_up GEMM + SiLU (validated) ----------------
__global__ __launch_bounds__(256) void k_mfma_glu(
    const u16* __restrict__ Abase, long long aStride, int lda,
    const u16* __restrict__ Wbase, long long wStride, int ldb,
    u16* __restrict__ Cbase, long long cStride, int ldc,
    const Job* __restrict__ rt, int Kd) {
  __shared__ __align__(16) char smem[(64 + 128 + 128) * 64];
  char* As = smem;
  char* Bg = smem + 64 * 64;
  char* Bu = smem + (64 + 128) * 64;

  const int job = blockIdx.z;
  const Job jb = rt[job];
  const u16* A = Abase + (long long)job * aStride;
  const u16* W = Wbase + (long long)jb.e * wStride;

  const int t = threadIdx.x;
  const int l = t & 63, w = t >> 6;
  const int wc = w;
  const int m0 = blockIdx.y * 64, n0 = blockIdx.x * 128;

  const int srow = (w << 4) + (l >> 2);
  const int scg = (l & 3) ^ ((l >> 3) & 3);
  const int cA = (((l >> 4) ^ ((l >> 1) & 3)) & 3) << 4;

  f32x4 accg[4][2] = {};
  f32x4 accu[4][2] = {};

  for (int k0 = 0; k0 < Kd; k0 += 32) {
    gload_lds16(A + (long long)(m0 + srow) * lda + k0 + scg * 8, As + (w << 10));
#pragma unroll
    for (int i = 0; i < 2; ++i) {
      gload_lds16(W + (long long)(n0 + i * 64 + srow) * ldb + k0 + scg * 8,
                  Bg + i * 4096 + (w << 10));
      gload_lds16(W + (long long)(1536 + n0 + i * 64 + srow) * ldb + k0 + scg * 8,
                  Bu + i * 4096 + (w << 10));
    }
    __syncthreads();

    bf16x8 af[4], bg[2], bu[2];
#pragma unroll
    for (int mi = 0; mi < 4; ++mi)
      af[mi] = *(const bf16x8*)(As + ((mi * 16 + (l & 15)) << 6) + cA);
#pragma unroll
    for (int ni = 0; ni < 2; ++ni) {
      bg[ni] = *(const bf16x8*)(Bg + ((wc * 32 + ni * 16 + (l & 15)) << 6) + cA);
      bu[ni] = *(const bf16x8*)(Bu + ((wc * 32 + ni * 16 + (l & 15)) << 6) + cA);
    }
#pragma unroll
    for (int mi = 0; mi < 4; ++mi)
#pragma unroll
      for (int ni = 0; ni < 2; ++ni) {
        accg[mi][ni] = __builtin_amdgcn_mfma_f32_16x16x32_bf16(af[mi], bg[ni], accg[mi][ni], 0, 0, 0);
        accu[mi][ni] = __builtin_amdgcn_mfma_f32_16x16x32_bf16(af[mi], bu[ni], accu[mi][ni], 0, 0, 0);
      }
    __syncthreads();
  }

  u16* C = Cbase + (long long)job * cStride;
#pragma unroll
  for (int mi = 0; mi < 4; ++mi) {
#pragma unroll
    for (int r = 0; r < 4; ++r) {
      int m = m0 + mi * 16 + ((l >> 4) << 2) + r;
#pragma unroll
      for (int ni = 0; ni < 2; ++ni) {
        int n = n0 + wc * 32 + ni * 16 + (l & 15);
        float g = accg[mi][ni][r];
        float u = accu[mi][ni][r];
        C[(long long)m * ldc + n] = f2b(g / (1.f + __expf(-g)) * u);
      }
    }
  }
}

// ---------------- RoPE in-place on bf16 qk (ld 1024) ----------------
__global__ __launch_bounds__(256) void k_rope(u16* __restrict__ qkBase,
                                              const float* __restrict__ cosT,
                                              const float* __restrict__ sinT) {
  int i = blockIdx.x;
  int job = blockIdx.y;
  u16* qk = qkBase + (long long)job * JB16;
  int t = threadIdx.x;
  int head = t >> 5, d = t & 31;
  int col = head * 64 + d;
  float c1 = cosT[i * 64 + d], c2 = cosT[i * 64 + d + 32];
  float s1 = sinT[i * 64 + d], s2 = sinT[i * 64 + d + 32];
  u16* row = qk + (long long)i * 1024;
  float x1 = b2f(row[col]), x2 = b2f(row[col + 32]);
  row[col] = f2b(x1 * c1 - x2 * s1);
  row[col + 32] = f2b(x2 * c2 + x1 * s2);
  float y1 = b2f(row[512 + col]), y2 = b2f(row[512 + col + 32]);
  row[512 + col] = f2b(y1 * c1 - y2 * s1);
  row[512 + col + 32] = f2b(y2 * c2 + y1 * s2);
}

// ---------------- MFMA flash attention ----------------
// block = (64-row q-tile, head, job), 4 waves x 16 q-rows each.
// Q/K from qk (ld 1024), V^T from vT (ld 512). All tiles [64][64] bf16 in LDS,
// 128B rows, chunk-XOR swizzle (chunk ^= row&7), staged via global_load_lds.
__global__ __launch_bounds__(256) void k_attn3(const u16* __restrict__ qkBase,
                                               const u16* __restrict__ vtBase,
                                               u16* __restrict__ ctxBase) {
  const int qt = blockIdx.x, head = blockIdx.y, job = blockIdx.z;
  const u16* qk = qkBase + (long long)job * JB16;
  const u16* vt = vtBase + (long long)job * JB16;
  u16* ctx = ctxBase + (long long)job * JB16;
  const int t = threadIdx.x, l = t & 63, w = t >> 6;
  const int q0 = qt * 64;

  __shared__ __align__(16) char Ql[8192];
  __shared__ __align__(16) char Kl[8192];
  __shared__ __align__(16) char Vl[8192];
  __shared__ __align__(16) char Pl[8192];

  // stage Q tile (pre-swizzled global chunk, linear LDS)
#pragma unroll
  for (int p = 0; p < 2; ++p) {
    int row = p * 32 + (w << 3) + (l >> 3);
    int c8 = (l & 7) ^ (row & 7);
    gload_lds16(qk + (long long)(q0 + row) * 1024 + head * 64 + c8 * 8,
                Ql + p * 4096 + (w << 10));
  }
  __syncthreads();
  bf16x8 aq0 = frag64(Ql, w << 4, 0, l);
  bf16x8 aq1 = frag64(Ql, w << 4, 1, l);

  f32x4 accO[4] = {};
  float mrun[4] = {-1e30f, -1e30f, -1e30f, -1e30f};
  float lrun[4] = {0.f, 0.f, 0.f, 0.f};

  for (int kt = 0; kt < 8; ++kt) {
    const int k0 = kt * 64;
    if (kt) __syncthreads();   // previous PV reads of Kl/Vl/Pl done
#pragma unroll
    for (int p = 0; p < 2; ++p) {
      int row = p * 32 + (w << 3) + (l >> 3);
      int c8 = (l & 7) ^ (row & 7);
      gload_lds16(qk + (long long)(k0 + row) * 1024 + 512 + head * 64 + c8 * 8,
                  Kl + p * 4096 + (w << 10));
      gload_lds16(vt + (long long)(head * 64 + row) * 512 + k0 + c8 * 8,
                  Vl + p * 4096 + (w << 10));
    }
    __syncthreads();

    // S = Q K^T for this wave's 16 q-rows x 64 k-cols
    f32x4 accS[4] = {};
#pragma unroll
    for (int ni = 0; ni < 4; ++ni)
      accS[ni] = __builtin_amdgcn_mfma_f32_16x16x32_bf16(aq0, frag64(Kl, ni * 16, 0, l), accS[ni], 0, 0, 0);
#pragma unroll
    for (int ni = 0; ni < 4; ++ni)
      accS[ni] = __builtin_amdgcn_mfma_f32_16x16x32_bf16(aq1, frag64(Kl, ni * 16, 1, l), accS[ni], 0, 0, 0);

    // online softmax per row r; row = (w<<4) + (l>>4)*4 + r, col = ni*16 + (l&15)
#pragma unroll
    for (int r = 0; r < 4; ++r) {
      float v0 = accS[0][r] * 0.125f, v1 = accS[1][r] * 0.125f;
      float v2 = accS[2][r] * 0.125f, v3 = accS[3][r] * 0.125f;
      float rm = fmaxf(fmaxf(v0, v1), fmaxf(v2, v3));
#pragma unroll
      for (int off = 8; off > 0; off >>= 1) rm = fmaxf(rm, __shfl_xor(rm, off, 64));
      float mnew = fmaxf(mrun[r], rm);
      float scf = __expf(mrun[r] - mnew);
      float p0 = __expf(v0 - mnew), p1 = __expf(v1 - mnew);
      float p2 = __expf(v2 - mnew), p3 = __expf(v3 - mnew);
      float rs = p0 + p1 + p2 + p3;
#pragma unroll
      for (int off = 8; off > 0; off >>= 1) rs += __shfl_xor(rs, off, 64);
      lrun[r] = lrun[r] * scf + rs;
      mrun[r] = mnew;
#pragma unroll
      for (int ni = 0; ni < 4; ++ni) accO[ni][r] *= scf;
      int prow = (w << 4) + ((l >> 4) << 2) + r;
      int pbase = prow * 128;
      int psw = (prow & 7) << 4;
      *(u16*)(Pl + pbase + ((( 0 + (l & 15)) * 2) ^ psw)) = f2b(p0);
      *(u16*)(Pl + pbase + (((16 + (l & 15)) * 2) ^ psw)) = f2b(p1);
      *(u16*)(Pl + pbase + (((32 + (l & 15)) * 2) ^ psw)) = f2b(p2);
      *(u16*)(Pl + pbase + (((48 + (l & 15)) * 2) ^ psw)) = f2b(p3);
    }
    __syncthreads();

    // O += P V  (A = P rows, B = V^T rows)
    bf16x8 ap0 = frag64(Pl, w << 4, 0, l);
    bf16x8 ap1 = frag64(Pl, w << 4, 1, l);
#pragma unroll
    for (int ni = 0; ni < 4; ++ni)
      accO[ni] = __builtin_amdgcn_mfma_f32_16x16x32_bf16(ap0, frag64(Vl, ni * 16, 0, l), accO[ni], 0, 0, 0);
#pragma unroll
    for (int ni = 0; ni < 4; ++ni)
      accO[ni] = __builtin_amdgcn_mfma_f32_16x16x32_bf16(ap1, frag64(Vl, ni * 16, 1, l), accO[ni], 0, 0, 0);
  }

#pragma unroll
  for (int r = 0; r < 4; ++r) {
    float inv = 1.0f / lrun[r];
    int m = q0 + (w << 4) + ((l >> 4) << 2) + r;
#pragma unroll
    for (int ni = 0; ni < 4; ++ni)
      ctx[(long long)m * 512 + head * 64 + ni * 16 + (l & 15)] = f2b(accO[ni][r] * inv);
  }
}

// ---------------- RMSNorm rows of 512: bf16 in-place ----------------
__global__ __launch_bounds__(256) void k_rms512(u16* __restrict__ base, long long strideB) {
  u16* x = base + (long long)blockIdx.y * strideB + (long long)blockIdx.x * 512;
  int t = threadIdx.x;
  __shared__ float buf[4];
  float a0 = b2f(x[t]), a1 = b2f(x[t + 256]);
  float ss = blockRedSum256(a0 * a0 + a1 * a1, buf);
  float r = rsqrtf(ss * (1.0f / 512.0f) + EPS);
  x[t] = f2b(a0 * r);
  x[t + 256] = f2b(a1 * r);
}

// ---------------- final: out = rms_norm(hidden+inj + oute1 + oute2), plus aux ----------------
__global__ __launch_bounds__(256) void k_final(const float* __restrict__ hid,
                                               const float* __restrict__ inj,
                                               const float* __restrict__ ws,
                                               const u16* __restrict__ jobsBase,
                                               float* __restrict__ out, int auxIdx) {
  int row = blockIdx.x;
  int b = row >> 9;
  int s = row & 511;
  const float* hr = hid + (long long)row * H_;
  const float* ir = inj + (long long)row * H_;
  const u16* o1 = jobsBase + (long long)(2 * b) * JB16 + R1O + (long long)s * H_;
  const u16* o2 = jobsBase + (long long)(2 * b + 1) * JB16 + R1O + (long long)s * H_;
  int t = threadIdx.x;
  __shared__ float buf[4];
  float v[4];
  float ss = 0.f;
#pragma unroll
  for (int c = 0; c < 4; c++) {
    int d = t + c * 256;
    v[c] = hr[d] + ir[d] + b2f(o1[d]) + b2f(o2[d]);
    ss += v[c] * v[c];
  }
  ss = blockRedSum256(ss, buf);
  float r = rsqrtf(ss * (1.0f / (float)H_) + EPS);
#pragma unroll
  for (int c = 0; c < 4; c++)
    out[(long long)row * H_ + t + c * 256] = v[c] * r;
  if (row == 0 && t == 0) out[auxIdx] = ws[AUX_OFF];
}

// ---------------- launch ----------------
extern "C" void kernel_launch(void* const* d_in, const int* in_sizes, int n_in,
                              void* d_out, int out_size, void* d_ws, size_t ws_size,
                              hipStream_t stream) {
  const float* hidden = (const float*)d_in[0];
  const float* inj    = (const float*)d_in[1];
  const float* cosT   = (const float*)d_in[2];
  const float* sinT   = (const float*)d_in[3];
  const float* gate_w = (const float*)d_in[4];
  const float* down_w = (const float*)d_in[5];
  const float* up_w   = (const float*)d_in[6];
  const float* qkv_w  = (const float*)d_in[7];
  const float* o_w    = (const float*)d_in[8];
  const float* gup_w  = (const float*)d_in[9];
  const float* mdw    = (const float*)d_in[10];
  float* out = (float*)d_out;
  float* ws  = (float*)d_ws;

  u16* hbf = (u16*)(ws + HBF_OFF);
  u16* wb  = (u16*)(ws + WB_OFF);
  const Job* rt = (const Job*)(ws + RT_OFF);
  u16* jobs = (u16*)(ws + PERJOB_OFF);

  u16* r1B   = jobs + R1O;     // qk / act / out_e
  u16* vtB   = jobs + VTO;     // v transposed
  u16* hsB   = jobs + HSBO;
  u16* hs2B  = jobs + HS2BO;
  u16* hs3B  = jobs + HS3BO;
  u16* ctxB  = jobs + CTXBO;

  k_add<<<2048, 256, 0, stream>>>(hidden, inj, hbf);
  k_routing<<<1, 64, 0, stream>>>(hidden, inj, gate_w, ws);

  k_f2b<<<2048, 256, 0, stream>>>(down_w, wb + DWB);
  k_f2b<<<3072, 256, 0, stream>>>(qkv_w,  wb + QWB);
  k_f2b<<<1024, 256, 0, stream>>>(o_w,    wb + OWB);
  k_f2b<<<6144, 256, 0, stream>>>(gup_w,  wb + GUB);
  k_f2b<<<3072, 256, 0, stream>>>(mdw,    wb + MDB);
  k_f2b<<<2048, 256, 0, stream>>>(up_w,   wb + UWB);

  // G1: hs = h[b] @ down_w[e].T   (512x512, K=1024)
  k_mfma<64, 0><<<dim3(4, 8, NJOBS), 256, 0, stream>>>(
      hbf, (long long)S_ * H_, 1, H_,
      wb + DWB, (long long)HSUB * H_, H_,
      hsB, JB16, HSUB, nullptr, 0, 0, rt, H_);

  // G2: qkv = hs @ qkv_w[e].T; q,k -> qk[512][1024], v -> vT[512][512]
  k_mfma_qkv<<<dim3(12, 4, NJOBS), 256, 0, stream>>>(
      hsB, JB16, HSUB,
      wb + QWB, (long long)3 * NH * HD * HSUB, HSUB,
      r1B, vtB, JB16, rt);

  k_rope<<<dim3(S_, NJOBS), 256, 0, stream>>>(r1B, cosT, sinT);
  k_attn3<<<dim3(8, NH, NJOBS), 256, 0, stream>>>(r1B, vtB, ctxB);

  // G3: hs2pre = hs + ctx @ o_w[e].T (512x512, K=512), rms in place
  k_mfma<64, 1><<<dim3(4, 8, NJOBS), 256, 0, stream>>>(
      ctxB, JB16, 0, HSUB,
      wb + OWB, (long long)HSUB * HSUB, HSUB,
      hs2B, JB16, HSUB, hsB, JB16, HSUB, rt, HSUB);
  k_rms512<<<dim3(S_, NJOBS), 256, 0, stream>>>(hs2B, JB16);

  // G4: act = silu(hs2@gate.T) * (hs2@up.T)  (512x1536, K=512)
  k_mfma_glu<<<dim3(12, 8, NJOBS), 256, 0, stream>>>(
      hs2B, JB16, HSUB,
      wb + GUB, (long long)2 * INTER * HSUB, HSUB,
      r1B, JB16, 1536, rt, HSUB);

  // G5: hs3pre = hs2 + act @ mdw[e].T (512x512, K=1536), rms in place
  k_mfma<64, 1><<<dim3(4, 8, NJOBS), 256, 0, stream>>>(
      r1B, JB16, 0, INTER,
      wb + MDB, (long long)HSUB * INTER, INTER,
      hs3B, JB16, HSUB, hs2B, JB16, HSUB, rt, INTER);
  k_rms512<<<dim3(S_, NJOBS), 256, 0, stream>>>(hs3B, JB16);

  // G6: out_e = (hs3 @ up_w[e].T) * jb.w (512x1024, K=512)
  k_mfma<128, 2><<<dim3(8, 4, NJOBS), 256, 0, stream>>>(
      hs3B, JB16, 0, HSUB,
      wb + UWB, (long long)H_ * HSUB, HSUB,
      r1B, JB16, H_, nullptr, 0, 0, rt, HSUB);

  k_final<<<B_ * S_, 256, 0, stream>>>(hidden, inj, ws, jobs, out, out_size - 1);
}